// Round 3
// baseline (292.657 us; speedup 1.0000x reference)
//
#include <hip/hip_runtime.h>

#define D 128
#define NH 4
#define DKH 32

typedef __attribute__((ext_vector_type(8))) short short8;
typedef __attribute__((ext_vector_type(4))) float floatx4;

__device__ __forceinline__ float bf2f(unsigned int u) {
    return __uint_as_float((u & 0xffffu) << 16);
}
__device__ __forceinline__ float bf2f_hi(unsigned int u) {
    return __uint_as_float(u & 0xffff0000u);
}
__device__ __forceinline__ unsigned short f2bf(float f) {
    unsigned int x = __float_as_uint(f);
    x += 0x7fffu + ((x >> 16) & 1u);
    return (unsigned short)(x >> 16);
}

// ---------------------------------------------------------------------------
// Fold rel_{k,q,v} into W,b -> WpT (bf16 transposed); w==3 transposes Wa.
// ---------------------------------------------------------------------------
__global__ void prep_weights_kernel(
    const float* __restrict__ Wk, const float* __restrict__ bk,
    const float* __restrict__ Wq, const float* __restrict__ bq,
    const float* __restrict__ Wv, const float* __restrict__ bv,
    const float* __restrict__ rk, const float* __restrict__ rq,
    const float* __restrict__ rv, const float* __restrict__ Wa,
    unsigned short* __restrict__ WpT, unsigned short* __restrict__ WaT,
    float* __restrict__ bp)
{
    int w = blockIdx.y;
    int j = threadIdx.x;            // output column 0..127
    int i = blockIdx.x;
    if (w == 3) {
        if (i < D) WaT[(size_t)j * D + i] = f2bf(Wa[(size_t)i * D + j]);
        return;
    }
    const float* W   = (w == 0) ? Wk : (w == 1) ? Wq : Wv;
    const float* b   = (w == 0) ? bk : (w == 1) ? bq : bv;
    const float* rel = (w == 0) ? rk : (w == 1) ? rq : rv;
    int h = j >> 5, f = j & 31;
    float acc = 0.f;
    if (i < D) {
        for (int dd = 0; dd < DKH; dd++)
            acc += W[i * D + h * DKH + dd] * rel[h * 1024 + dd * DKH + f];
        WpT[((size_t)(w * D + j)) * D + i] = f2bf(acc);
    } else {
        for (int dd = 0; dd < DKH; dd++)
            acc += b[h * DKH + dd] * rel[h * 1024 + dd * DKH + f];
        bp[w * D + j] = acc;
    }
}

// ---------------------------------------------------------------------------
// MFMA GEMM: [qt | kv] = h @ W'{k,q,v} + b', plus fused row norms.
// 64 rows/block, 8 waves, wave-per-t-slice: wave w owns output columns
// w*16..w*16+15 for ALL 64 rows.  Weight loads: 12 short8 per wave,
// ZERO cross-wave redundancy, issued ONCE at kernel top and pinned
// above the h-staging via sched_barrier(0) -> L2 latency hides under the
// HBM staging round-trip.  Outputs store DIRECTLY to global.
// LDS = hA only (17.4 KB), ONE barrier.
// ---------------------------------------------------------------------------
#define ASTR 136
__global__ __launch_bounds__(512) void gemm_mfma_kernel(
    const float* __restrict__ h, const unsigned short* __restrict__ WpT,
    const float* __restrict__ bp,
    unsigned short* __restrict__ qt, unsigned int* __restrict__ kv,
    float* __restrict__ inv_norm, int N)
{
    __shared__ unsigned short hA[64 * ASTR];   // 17.4 KB

    int row0 = blockIdx.x * 64;
    int tid = threadIdx.x;
    int lane = tid & 63, w = tid >> 6;
    int m = lane & 15, quad = lane >> 4;

    // --- this wave's 12 weight fragments (t-slice = w), issued up front ----
    const unsigned short* kb = WpT + (size_t)(w * 16 + m) * D + quad * 8;
    const unsigned short* qb = kb + (size_t)D * D;
    const unsigned short* vb = kb + (size_t)2 * D * D;
    short8 k0 = *(const short8*)(kb);      short8 k1 = *(const short8*)(kb + 32);
    short8 k2 = *(const short8*)(kb + 64); short8 k3 = *(const short8*)(kb + 96);
    short8 q0 = *(const short8*)(qb);      short8 q1 = *(const short8*)(qb + 32);
    short8 q2 = *(const short8*)(qb + 64); short8 q3 = *(const short8*)(qb + 96);
    short8 v0 = *(const short8*)(vb);      short8 v1 = *(const short8*)(vb + 32);
    short8 v2 = *(const short8*)(vb + 64); short8 v3 = *(const short8*)(vb + 96);
    int j = w * 16 + m;
    float bkv = bp[j], bqv = bp[D + j], bvv = bp[2 * D + j];
    __builtin_amdgcn_sched_barrier(0);   // pin the loads above the staging

    // --- stage h tile into LDS as bf16 -------------------------------------
    for (int i = tid; i < 64 * 32; i += 512) {
        int r = i >> 5, c4 = (i & 31) << 2;
        int n = row0 + r;
        float4 v = make_float4(0.f, 0.f, 0.f, 0.f);
        if (n < N) v = *(const float4*)(h + (size_t)n * D + c4);
        ushort4 bv4;
        bv4.x = f2bf(v.x); bv4.y = f2bf(v.y); bv4.z = f2bf(v.z); bv4.w = f2bf(v.w);
        *(ushort4*)&hA[r * ASTR + c4] = bv4;
    }
    __syncthreads();   // the only barrier; hA stays live to kernel end

    unsigned int* qtu = (unsigned int*)qt;

#pragma unroll
    for (int tile = 0; tile < 4; tile++) {
        const unsigned short* ab = &hA[(tile * 16 + m) * ASTR + quad * 8];
        short8 a0 = *(const short8*)(ab);
        short8 a1 = *(const short8*)(ab + 32);
        short8 a2 = *(const short8*)(ab + 64);
        short8 a3 = *(const short8*)(ab + 96);
        floatx4 aK = (floatx4){0.f, 0.f, 0.f, 0.f};
        floatx4 aQ = (floatx4){0.f, 0.f, 0.f, 0.f};
        floatx4 aV = (floatx4){0.f, 0.f, 0.f, 0.f};
        aK = __builtin_amdgcn_mfma_f32_16x16x32_bf16(a0, k0, aK, 0, 0, 0);
        aQ = __builtin_amdgcn_mfma_f32_16x16x32_bf16(a0, q0, aQ, 0, 0, 0);
        aV = __builtin_amdgcn_mfma_f32_16x16x32_bf16(a0, v0, aV, 0, 0, 0);
        aK = __builtin_amdgcn_mfma_f32_16x16x32_bf16(a1, k1, aK, 0, 0, 0);
        aQ = __builtin_amdgcn_mfma_f32_16x16x32_bf16(a1, q1, aQ, 0, 0, 0);
        aV = __builtin_amdgcn_mfma_f32_16x16x32_bf16(a1, v1, aV, 0, 0, 0);
        aK = __builtin_amdgcn_mfma_f32_16x16x32_bf16(a2, k2, aK, 0, 0, 0);
        aQ = __builtin_amdgcn_mfma_f32_16x16x32_bf16(a2, q2, aQ, 0, 0, 0);
        aV = __builtin_amdgcn_mfma_f32_16x16x32_bf16(a2, v2, aV, 0, 0, 0);
        aK = __builtin_amdgcn_mfma_f32_16x16x32_bf16(a3, k3, aK, 0, 0, 0);
        aQ = __builtin_amdgcn_mfma_f32_16x16x32_bf16(a3, q3, aQ, 0, 0, 0);
        aV = __builtin_amdgcn_mfma_f32_16x16x32_bf16(a3, v3, aV, 0, 0, 0);
#pragma unroll
        for (int r = 0; r < 4; r++) {
            int row = tile * 16 + quad * 4 + r;
            int n = row0 + row;
            float kval = aK[r] + bkv;
            float qval = aQ[r] + bqv;
            float vval = aV[r] + bvv;
            float qpart = __shfl_xor(qval, 1);
            unsigned int kvp = (unsigned int)f2bf(kval)
                             | ((unsigned int)f2bf(vval) << 16);
            unsigned int qp  = (unsigned int)f2bf(qval)
                             | ((unsigned int)f2bf(qpart) << 16);
            if (n < N) {
                kv[(size_t)n * D + w * 16 + m] = kvp;            // 4x64B segs
                if (!(m & 1))
                    qtu[(size_t)n * 64 + w * 8 + (m >> 1)] = qp; // 4x32B segs
            }
        }
    }

    // --- row norms: waves 0..3 own rows w*16..w*16+15 (hA still live) ------
    if (w < 4) {
        for (int rr = 0; rr < 16; rr += 4) {
            float s0, s1, s2, s3;
            {
                unsigned int u0 = *(const unsigned int*)&hA[(w * 16 + rr + 0) * ASTR + lane * 2];
                unsigned int u1 = *(const unsigned int*)&hA[(w * 16 + rr + 1) * ASTR + lane * 2];
                unsigned int u2 = *(const unsigned int*)&hA[(w * 16 + rr + 2) * ASTR + lane * 2];
                unsigned int u3 = *(const unsigned int*)&hA[(w * 16 + rr + 3) * ASTR + lane * 2];
                float a, b;
                a = bf2f(u0); b = bf2f_hi(u0); s0 = a * a + b * b;
                a = bf2f(u1); b = bf2f_hi(u1); s1 = a * a + b * b;
                a = bf2f(u2); b = bf2f_hi(u2); s2 = a * a + b * b;
                a = bf2f(u3); b = bf2f_hi(u3); s3 = a * a + b * b;
            }
#pragma unroll
            for (int off = 1; off < 64; off <<= 1) {
                s0 += __shfl_xor(s0, off);
                s1 += __shfl_xor(s1, off);
                s2 += __shfl_xor(s2, off);
                s3 += __shfl_xor(s3, off);
            }
            if (lane < 4) {
                float sv = (lane == 0) ? s0 : (lane == 1) ? s1 : (lane == 2) ? s2 : s3;
                int n = row0 + w * 16 + rr + lane;
                if (n < N) inv_norm[n] = 1.0f / fmaxf(sqrtf(sv), 1e-12f);
            }
        }
    }
}

// ---------------------------------------------------------------------------
// Histogram: src presence via plain byte store (benign race; deg only ever
// tested != 0), dst incidence via atomicAdd (CSR sizes need exact counts).
// ---------------------------------------------------------------------------
__global__ void deg_hist_kernel(const int* __restrict__ src, const int* __restrict__ dst,
                                unsigned char* __restrict__ sflag,
                                int* __restrict__ cnt_dst, int E)
{
    int e = blockIdx.x * blockDim.x + threadIdx.x;
    if (e >= E) return;
    sflag[src[e]] = 1;
    atomicAdd(&cnt_dst[dst[e]], 1);
}

// ---------------------------------------------------------------------------
__global__ __launch_bounds__(1024) void scan_blocks_kernel(
    const unsigned char* __restrict__ sflag, const int* __restrict__ cnt_dst,
    int* __restrict__ rowptr, int* __restrict__ deg,
    int* __restrict__ btot, int* __restrict__ zcount, int N)
{
    __shared__ int wtot[16];
    __shared__ int wscan[16];
    int tid = threadIdx.x, lane = tid & 63, wv = tid >> 6;
    int i = blockIdx.x * 1024 + tid;
    int cs = 0, cd = 0;
    if (i < N) { cs = sflag[i]; cd = cnt_dst[i]; }
    int x = cd;
#pragma unroll
    for (int off = 1; off < 64; off <<= 1) {
        int y = __shfl_up(x, off);
        if (lane >= off) x += y;
    }
    if (lane == 63) wtot[wv] = x;
    __syncthreads();
    if (wv == 0) {
        int t = (lane < 16) ? wtot[lane] : 0;
#pragma unroll
        for (int off = 1; off < 16; off <<= 1) {
            int y = __shfl_up(t, off);
            if (lane >= off) t += y;
        }
        if (lane < 16) wscan[lane] = t;
    }
    __syncthreads();
    int woff = (wv == 0) ? 0 : wscan[wv - 1];
    if (i < N) {
        rowptr[i] = woff + x - cd;
        deg[i] = (cs | (cd > 0)) ? 1 : 0;   // 0/1 indicator; only ever tested != 0
    }
    if (tid == 0) btot[blockIdx.x] = wscan[15];
    int zc = (i < N && cs == 0 && cd == 0) ? 1 : 0;
#pragma unroll
    for (int off = 1; off < 64; off <<= 1) zc += __shfl_xor(zc, off);
    if (lane == 0 && zc) atomicAdd(zcount, zc);
}

// ---------------------------------------------------------------------------
__global__ void scan_final_kernel(const int* __restrict__ btot,
                                  int* __restrict__ boff, int* __restrict__ rowptr,
                                  const int* __restrict__ zcount,
                                  const float* __restrict__ fsb,
                                  float* __restrict__ flags, int N, int nb)
{
    int lane = threadIdx.x;   // 64
    int v = (lane < nb) ? btot[lane] : 0;
    int x = v;
#pragma unroll
    for (int off = 1; off < 64; off <<= 1) {
        int y = __shfl_up(x, off);
        if (lane >= off) x += y;
    }
    if (lane < nb) boff[lane] = x - v;
    if (lane == 63) rowptr[N] = x;    // grand total = E
    if (lane == 0) {
        float z = (float)zcount[0];
        float sparsity = z / (float)N;
        flags[0] = (sparsity > 0.3f) ? fsb[0] : 0.f;
        flags[1] = fmaxf((float)N - z, 1.f);
    }
}

__global__ void scan_add_kernel(int* __restrict__ rowptr,
                                const int* __restrict__ boff, int N)
{
    int i = blockIdx.x * blockDim.x + threadIdx.x;
    if (i < N) rowptr[i] += boff[i >> 10];
}

// ---------------------------------------------------------------------------
__global__ void scatter_kernel(const int* __restrict__ src, const int* __restrict__ dst,
                               const int* __restrict__ rowptr, int* __restrict__ cursor,
                               int* __restrict__ esrc, int E)
{
    int e = blockIdx.x * blockDim.x + threadIdx.x;
    if (e >= E) return;
    int d = dst[e];
    int pos = rowptr[d] + atomicAdd(&cursor[d], 1);
    esrc[pos] = src[e];
}

// ---------------------------------------------------------------------------
// Fused softmax + aggregation, gather-based, ZERO atomics.
// One wave per dst node, 32 lanes/edge.  MAIN LOOP: 8 edges/iter -> 4
// independent kv gathers in flight per half (r2 post-mortem: 60 us with all
// pipes <50% = latency-bound on the esrc->kv dependent chain with only 2
// gathers outstanding; this doubles MLP in steady state).  Tails 4/2/1.
// ---------------------------------------------------------------------------
__global__ __launch_bounds__(256) void dst_agg_kernel(
    const unsigned int* __restrict__ kv, const unsigned short* __restrict__ qt,
    const float* __restrict__ h, const float* __restrict__ inv_norm,
    const int* __restrict__ rowptr, const int* __restrict__ esrc,
    const float* __restrict__ flags,
    unsigned int* __restrict__ agg, int N)
{
    int n = (blockIdx.x * blockDim.x + threadIdx.x) >> 6;
    int lane = threadIdx.x & 63;
    if (n >= N) return;
    int half = lane >> 5, c = lane & 31;
    int beg = rowptr[n], end = rowptr[n + 1];
    uint2 qw = *(const uint2*)(qt + (size_t)n * D + c * 4);
    float q0 = bf2f(qw.x), q1 = bf2f_hi(qw.x);
    float q2 = bf2f(qw.y), q3 = bf2f_hi(qw.y);
    float boost = flags[0];
    float hn0 = 0.f, hn1 = 0.f, hn2 = 0.f, hn3 = 0.f, innd = 0.f;
    if (boost != 0.f) {
        float4 hh = *(const float4*)(h + (size_t)n * D + c * 4);
        hn0 = hh.x; hn1 = hh.y; hn2 = hh.z; hn3 = hh.w; innd = inv_norm[n];
    }
    const float SC = 0.17677669529663687f;   // 1/sqrt(32)
    float a0 = 0.f, a1 = 0.f, a2 = 0.f, a3 = 0.f, den = 0.f;
    int i = beg;
    // ---- main: 8 edges / iteration (4 gathers in flight per half) ---------
    for (; i + 7 < end; i += 8) {
        int sA = esrc[i + half];
        int sB = esrc[i + 2 + half];
        int sC = esrc[i + 4 + half];
        int sD = esrc[i + 6 + half];
        uint4 wA = *(const uint4*)(kv + (size_t)sA * D + c * 4);
        uint4 wB = *(const uint4*)(kv + (size_t)sB * D + c * 4);
        uint4 wC = *(const uint4*)(kv + (size_t)sC * D + c * 4);
        uint4 wD = *(const uint4*)(kv + (size_t)sD * D + c * 4);
        float dA = q0 * bf2f(wA.x) + q1 * bf2f(wA.y)
                 + q2 * bf2f(wA.z) + q3 * bf2f(wA.w);
        float dB = q0 * bf2f(wB.x) + q1 * bf2f(wB.y)
                 + q2 * bf2f(wB.z) + q3 * bf2f(wB.w);
        float dC = q0 * bf2f(wC.x) + q1 * bf2f(wC.y)
                 + q2 * bf2f(wC.z) + q3 * bf2f(wC.w);
        float dD = q0 * bf2f(wD.x) + q1 * bf2f(wD.y)
                 + q2 * bf2f(wD.z) + q3 * bf2f(wD.w);
        dA += __shfl_xor(dA, 1);  dB += __shfl_xor(dB, 1);
        dC += __shfl_xor(dC, 1);  dD += __shfl_xor(dD, 1);
        dA += __shfl_xor(dA, 2);  dB += __shfl_xor(dB, 2);
        dC += __shfl_xor(dC, 2);  dD += __shfl_xor(dD, 2);
        dA += __shfl_xor(dA, 4);  dB += __shfl_xor(dB, 4);
        dC += __shfl_xor(dC, 4);  dD += __shfl_xor(dD, 4);
        float attA = dA * SC, attB = dB * SC;
        float attC = dC * SC, attD = dD * SC;
        if (boost != 0.f) {
            float4 xA = *(const float4*)(h + (size_t)sA * D + c * 4);
            float4 xB = *(const float4*)(h + (size_t)sB * D + c * 4);
            float4 xC = *(const float4*)(h + (size_t)sC * D + c * 4);
            float4 xD = *(const float4*)(h + (size_t)sD * D + c * 4);
            float fA = hn0 * xA.x + hn1 * xA.y + hn2 * xA.z + hn3 * xA.w;
            float fB = hn0 * xB.x + hn1 * xB.y + hn2 * xB.z + hn3 * xB.w;
            float fC = hn0 * xC.x + hn1 * xC.y + hn2 * xC.z + hn3 * xC.w;
            float fD = hn0 * xD.x + hn1 * xD.y + hn2 * xD.z + hn3 * xD.w;
#pragma unroll
            for (int off = 1; off < 32; off <<= 1) {
                fA += __shfl_xor(fA, off);
                fB += __shfl_xor(fB, off);
                fC += __shfl_xor(fC, off);
                fD += __shfl_xor(fD, off);
            }
            attA += fA * inv_norm[sA] * innd * boost;
            attB += fB * inv_norm[sB] * innd * boost;
            attC += fC * inv_norm[sC] * innd * boost;
            attD += fD * inv_norm[sD] * innd * boost;
        }
        attA = fminf(fmaxf(attA, -60.f), 60.f);
        attB = fminf(fmaxf(attB, -60.f), 60.f);
        attC = fminf(fmaxf(attC, -60.f), 60.f);
        attD = fminf(fmaxf(attD, -60.f), 60.f);
        float pA = __expf(attA), pB = __expf(attB);
        float pC = __expf(attC), pD = __expf(attD);
        den += (pA + pB) + (pC + pD);
        a0 += pA * bf2f_hi(wA.x) + pB * bf2f_hi(wB.x)
            + pC * bf2f_hi(wC.x) + pD * bf2f_hi(wD.x);
        a1 += pA * bf2f_hi(wA.y) + pB * bf2f_hi(wB.y)
            + pC * bf2f_hi(wC.y) + pD * bf2f_hi(wD.y);
        a2 += pA * bf2f_hi(wA.z) + pB * bf2f_hi(wB.z)
            + pC * bf2f_hi(wC.z) + pD * bf2f_hi(wD.z);
        a3 += pA * bf2f_hi(wA.w) + pB * bf2f_hi(wB.w)
            + pC * bf2f_hi(wC.w) + pD * bf2f_hi(wD.w);
    }
    // ---- tail: 4 edges ----------------------------------------------------
    for (; i + 3 < end; i += 4) {
        int sA = esrc[i + half];
        int sB = esrc[i + 2 + half];
        uint4 wA = *(const uint4*)(kv + (size_t)sA * D + c * 4);
        uint4 wB = *(const uint4*)(kv + (size_t)sB * D + c * 4);
        float dA = q0 * bf2f(wA.x) + q1 * bf2f(wA.y)
                 + q2 * bf2f(wA.z) + q3 * bf2f(wA.w);
        float dB = q0 * bf2f(wB.x) + q1 * bf2f(wB.y)
                 + q2 * bf2f(wB.z) + q3 * bf2f(wB.w);
        dA += __shfl_xor(dA, 1);  dB += __shfl_xor(dB, 1);
        dA += __shfl_xor(dA, 2);  dB += __shfl_xor(dB, 2);
        dA += __shfl_xor(dA, 4);  dB += __shfl_xor(dB, 4);
        float attA = dA * SC, attB = dB * SC;
        if (boost != 0.f) {
            float4 xA = *(const float4*)(h + (size_t)sA * D + c * 4);
            float4 xB = *(const float4*)(h + (size_t)sB * D + c * 4);
            float fA = hn0 * xA.x + hn1 * xA.y + hn2 * xA.z + hn3 * xA.w;
            float fB = hn0 * xB.x + hn1 * xB.y + hn2 * xB.z + hn3 * xB.w;
#pragma unroll
            for (int off = 1; off < 32; off <<= 1) {
                fA += __shfl_xor(fA, off);
                fB += __shfl_xor(fB, off);
            }
            attA += fA * inv_norm[sA] * innd * boost;
            attB += fB * inv_norm[sB] * innd * boost;
        }
        attA = fminf(fmaxf(attA, -60.f), 60.f);
        attB = fminf(fmaxf(attB, -60.f), 60.f);
        float pA = __expf(attA), pB = __expf(attB);
        den += pA + pB;
        a0 += pA * bf2f_hi(wA.x) + pB * bf2f_hi(wB.x);
        a1 += pA * bf2f_hi(wA.y) + pB * bf2f_hi(wB.y);
        a2 += pA * bf2f_hi(wA.z) + pB * bf2f_hi(wB.z);
        a3 += pA * bf2f_hi(wA.w) + pB * bf2f_hi(wB.w);
    }
    for (; i + 1 < end; i += 2) {
        int sA = esrc[i + half];
        uint4 wA = *(const uint4*)(kv + (size_t)sA * D + c * 4);
        float dA = q0 * bf2f(wA.x) + q1 * bf2f(wA.y)
                 + q2 * bf2f(wA.z) + q3 * bf2f(wA.w);
        dA += __shfl_xor(dA, 1);
        dA += __shfl_xor(dA, 2);
        dA += __shfl_xor(dA, 4);
        float attA = dA * SC;
        if (boost != 0.f) {
            float4 xA = *(const float4*)(h + (size_t)sA * D + c * 4);
            float fA = hn0 * xA.x + hn1 * xA.y + hn2 * xA.z + hn3 * xA.w;
#pragma unroll
            for (int off = 1; off < 32; off <<= 1) fA += __shfl_xor(fA, off);
            attA += fA * inv_norm[sA] * innd * boost;
        }
        attA = fminf(fmaxf(attA, -60.f), 60.f);
        float pA = __expf(attA);
        den += pA;
        a0 += pA * bf2f_hi(wA.x);
        a1 += pA * bf2f_hi(wA.y);
        a2 += pA * bf2f_hi(wA.z);
        a3 += pA * bf2f_hi(wA.w);
    }
    if (i < end && half == 0) {
        int sA = esrc[i];
        uint4 wA = *(const uint4*)(kv + (size_t)sA * D + c * 4);
        float dA = q0 * bf2f(wA.x) + q1 * bf2f(wA.y)
                 + q2 * bf2f(wA.z) + q3 * bf2f(wA.w);
        dA += __shfl_xor(dA, 1);
        dA += __shfl_xor(dA, 2);
        dA += __shfl_xor(dA, 4);
        float attA = dA * SC;
        if (boost != 0.f) {
            float4 xA = *(const float4*)(h + (size_t)sA * D + c * 4);
            float fA = hn0 * xA.x + hn1 * xA.y + hn2 * xA.z + hn3 * xA.w;
#pragma unroll
            for (int off = 1; off < 32; off <<= 1) fA += __shfl_xor(fA, off);
            attA += fA * inv_norm[sA] * innd * boost;
        }
        attA = fminf(fmaxf(attA, -60.f), 60.f);
        float pA = __expf(attA);
        den += pA;
        a0 += pA * bf2f_hi(wA.x);
        a1 += pA * bf2f_hi(wA.y);
        a2 += pA * bf2f_hi(wA.z);
        a3 += pA * bf2f_hi(wA.w);
    }
    den += __shfl_xor(den, 32);
    a0  += __shfl_xor(a0, 32);
    a1  += __shfl_xor(a1, 32);
    a2  += __shfl_xor(a2, 32);
    a3  += __shfl_xor(a3, 32);
    if (half == 0) {
        float r = 1.0f / fmaxf(den, 1e-38f);
        uint2 o;
        o.x = (unsigned int)f2bf(a0 * r) | ((unsigned int)f2bf(a1 * r) << 16);
        o.y = (unsigned int)f2bf(a2 * r) | ((unsigned int)f2bf(a3 * r) << 16);
        *(uint2*)(agg + (size_t)n * (D / 2) + c * 2) = o;
    }
}

// ---------------------------------------------------------------------------
// out = LN(agg @ Wa + ba) via MFMA.  64 rows/block, 4 waves; pre-LN values
// stored as bf16 ALIASED over aB (same stride, wave-private rows -> legal
// without barrier).  LDS 17.4 KB -> 8 blocks/CU.
// ---------------------------------------------------------------------------
__global__ __launch_bounds__(256) void out_ln_kernel(
    const unsigned int* __restrict__ agg,      // packed bf16 pairs
    const unsigned short* __restrict__ WaT, const float* __restrict__ ba,
    const float* __restrict__ ln_g, const float* __restrict__ ln_b,
    const int* __restrict__ deg, float* __restrict__ out,
    float* __restrict__ gcpart, int N)
{
    __shared__ unsigned short aB[64 * ASTR];
    unsigned short* os = aB;   // alias: wave w reads/writes only rows w*16..+15
    int row0 = blockIdx.x * 64;
    int tid = threadIdx.x;
    for (int i = tid; i < 64 * 16; i += 256) {
        int r = i >> 4, c8 = (i & 15) << 3;
        int n = row0 + r;
        uint4 v = make_uint4(0u, 0u, 0u, 0u);
        if (n < N) v = *(const uint4*)(agg + (size_t)n * D / 2 + (c8 >> 1));
        *(uint4*)&aB[r * ASTR + c8] = v;
    }
    __syncthreads();
    int lane = tid & 63, w = tid >> 6;
    int m = lane & 15, quad = lane >> 4;

    short8 afrag[4];
    const unsigned short* ab = &aB[(w * 16 + m) * ASTR + quad * 8];
#pragma unroll
    for (int c = 0; c < 4; c++)
        afrag[c] = *(const short8*)(ab + c * 32);

    const unsigned short* wbase = WaT + (size_t)m * D + quad * 8;
    short8 A0, A1, A2, A3, B0, B1, B2, B3;
    A0 = *(const short8*)(wbase);
    A1 = *(const short8*)(wbase + 32);
    A2 = *(const short8*)(wbase + 64);
    A3 = *(const short8*)(wbase + 96);
#pragma unroll 1
    for (int t = 0; t < 8; t += 2) {
        const unsigned short* nb = wbase + (size_t)(t + 1) * 16 * D;
        B0 = *(const short8*)(nb);
        B1 = *(const short8*)(nb + 32);
        B2 = *(const short8*)(nb + 64);
        B3 = *(const short8*)(nb + 96);
        {
            floatx4 acc = (floatx4){0.f, 0.f, 0.f, 0.f};
            acc = __builtin_amdgcn_mfma_f32_16x16x32_bf16(afrag[0], A0, acc, 0, 0, 0);
            acc = __builtin_amdgcn_mfma_f32_16x16x32_bf16(afrag[1], A1, acc, 0, 0, 0);
            acc = __builtin_amdgcn_mfma_f32_16x16x32_bf16(afrag[2], A2, acc, 0, 0, 0);
            acc = __builtin_amdgcn_mfma_f32_16x16x32_bf16(afrag[3], A3, acc, 0, 0, 0);
            int j = t * 16 + m;
            float bj = ba[j];
#pragma unroll
            for (int r = 0; r < 4; r++)
                os[(w * 16 + quad * 4 + r) * ASTR + j] = f2bf(acc[r] + bj);
        }
        if (t + 2 < 8) {
            const unsigned short* na = wbase + (size_t)(t + 2) * 16 * D;
            A0 = *(const short8*)(na);
            A1 = *(const short8*)(na + 32);
            A2 = *(const short8*)(na + 64);
            A3 = *(const short8*)(na + 96);
        }
        {
            floatx4 acc = (floatx4){0.f, 0.f, 0.f, 0.f};
            acc = __builtin_amdgcn_mfma_f32_16x16x32_bf16(afrag[0], B0, acc, 0, 0, 0);
            acc = __builtin_amdgcn_mfma_f32_16x16x32_bf16(afrag[1], B1, acc, 0, 0, 0);
            acc = __builtin_amdgcn_mfma_f32_16x16x32_bf16(afrag[2], B2, acc, 0, 0, 0);
            acc = __builtin_amdgcn_mfma_f32_16x16x32_bf16(afrag[3], B3, acc, 0, 0, 0);
            int j = (t + 1) * 16 + m;
            float bj = ba[j];
#pragma unroll
            for (int r = 0; r < 4; r++)
                os[(w * 16 + quad * 4 + r) * ASTR + j] = f2bf(acc[r] + bj);
        }
    }
    int j2 = lane * 2;
    float g0 = ln_g[j2], g1 = ln_g[j2 + 1];
    float b0 = ln_b[j2], b1 = ln_b[j2 + 1];
    float gcs0 = 0.f, gcs1 = 0.f;
    for (int rr = 0; rr < 16; rr++) {
        int r = w * 16 + rr;
        int n = row0 + r;
        if (n >= N) break;
        unsigned int u = *(const unsigned int*)&os[r * ASTR + j2];
        float x0 = bf2f(u), x1 = bf2f_hi(u);
        float s = x0 + x1, s2 = x0 * x0 + x1 * x1;
#pragma unroll
        for (int off = 1; off < 64; off <<= 1) {
            s  += __shfl_xor(s, off);
            s2 += __shfl_xor(s2, off);
        }
        float mu = s * (1.f / 128.f);
        float var = s2 * (1.f / 128.f) - mu * mu;
        float rstd = rsqrtf(fmaxf(var, 0.f) + 1e-5f);
        float y0 = (x0 - mu) * rstd * g0 + b0;
        float y1 = (x1 - mu) * rstd * g1 + b1;
        *(float2*)(out + (size_t)n * D + j2) = make_float2(y0, y1);
        if (deg[n] != 0) { gcs0 += y0; gcs1 += y1; }
    }
    int slot = blockIdx.x & 63;
    if (gcs0 != 0.f || gcs1 != 0.f) {
        atomicAdd(&gcpart[slot * D + j2],     gcs0);
        atomicAdd(&gcpart[slot * D + j2 + 1], gcs1);
    }
}

__global__ void gc_final_kernel(const float* __restrict__ gcpart,
                                const float* __restrict__ flags,
                                float* __restrict__ gc)
{
    int j = threadIdx.x;  // 128
    float s = 0.f;
    for (int i = 0; i < 64; i++) s += gcpart[i * D + j];
    gc[j] = s / flags[1];
}

// ---------------------------------------------------------------------------
__global__ void fixup_kernel(const float* __restrict__ h,
                             const int* __restrict__ deg,
                             const float* __restrict__ gc,
                             float* __restrict__ out, int N)
{
    int n = blockIdx.x * blockDim.x + threadIdx.x;
    if (n >= N) return;
    if (deg[n] != 0) return;
    for (int j = 0; j < D; j += 4) {
        float4 hv = *(const float4*)(h + (size_t)n * D + j);
        float4 gv = *(const float4*)(gc + j);
        float4 o;
        o.x = 0.9f * hv.x + 0.1f * gv.x;
        o.y = 0.9f * hv.y + 0.1f * gv.y;
        o.z = 0.9f * hv.z + 0.1f * gv.z;
        o.w = 0.9f * hv.w + 0.1f * gv.w;
        *(float4*)(out + (size_t)n * D + j) = o;
    }
}

// ---------------------------------------------------------------------------
extern "C" void kernel_launch(void* const* d_in, const int* in_sizes, int n_in,
                              void* d_out, int out_size, void* d_ws, size_t ws_size,
                              hipStream_t stream)
{
    const float* h       = (const float*)d_in[0];
    const int* src_idx   = (const int*)d_in[1];
    const int* dst_idx   = (const int*)d_in[2];
    const float* Wk      = (const float*)d_in[3];
    const float* bk      = (const float*)d_in[4];
    const float* Wq      = (const float*)d_in[5];
    const float* bq      = (const float*)d_in[6];
    const float* Wv      = (const float*)d_in[7];
    const float* bv      = (const float*)d_in[8];
    const float* rk      = (const float*)d_in[9];
    const float* rq      = (const float*)d_in[10];
    const float* rv      = (const float*)d_in[11];
    const float* Wa      = (const float*)d_in[12];
    const float* ba      = (const float*)d_in[13];
    const float* ln_g    = (const float*)d_in[14];
    const float* ln_b    = (const float*)d_in[15];
    const float* fsb     = (const float*)d_in[16];
    float* out           = (float*)d_out;

    int N = in_sizes[0] / D;
    int E = in_sizes[1];
    int nb = (N + 1023) >> 10;   // scan blocks (<= 64)

    // ---- workspace: small control buffers first ---------------------------
    char* p = (char*)d_ws;
    auto alloc = [&](size_t bytes) { char* q = p; p += (bytes + 15) & ~(size_t)15; return q; };

    unsigned short* WpT = (unsigned short*)alloc(3 * D * D * 2);
    unsigned short* WaT = (unsigned short*)alloc(D * D * 2);
    float* bp       = (float*)alloc(3 * D * 4);
    float* gc       = (float*)alloc(D * 4);
    float* flags    = (float*)alloc(2 * 4);
    int*   btot     = (int*)alloc(64 * 4);
    int*   boff     = (int*)alloc(64 * 4);
    float* inv_norm = (float*)alloc((size_t)N * 4);
    int*   rowptr   = (int*)alloc(((size_t)N + 1) * 4);
    int*   deg      = (int*)alloc((size_t)N * 4);
    // zero region: sflag, cnt_dst, cursor, zcount, gcpart (contiguous)
    char* z1 = p;
    unsigned char* sflag = (unsigned char*)alloc((size_t)N);
    int*   cnt_dst = (int*)alloc((size_t)N * 4);
    int*   cursor  = (int*)alloc((size_t)N * 4);
    int*   zcount  = (int*)alloc(4);
    float* gcpart  = (float*)alloc(64 * D * 4);
    size_t z1_bytes = (size_t)(p - z1);
    // big arrays
    unsigned short* qt = (unsigned short*)alloc((size_t)N * D * 2);
    unsigned int*   kv = (unsigned int*)alloc((size_t)N * D * 4);
    int*   esrc        = (int*)alloc((size_t)E * 4);
    unsigned int* agg  = (unsigned int*)alloc((size_t)N * D * 2);

    hipMemsetAsync(z1, 0, z1_bytes, stream);

    prep_weights_kernel<<<dim3(129, 4), 128, 0, stream>>>(Wk, bk, Wq, bq, Wv, bv,
                                                          rk, rq, rv, Wa,
                                                          WpT, WaT, bp);
    gemm_mfma_kernel<<<(N + 63) / 64, 512, 0, stream>>>(h, WpT, bp, qt, kv,
                                                        inv_norm, N);
    deg_hist_kernel<<<(E + 255) / 256, 256, 0, stream>>>(src_idx, dst_idx,
                                                         sflag, cnt_dst, E);
    scan_blocks_kernel<<<nb, 1024, 0, stream>>>(sflag, cnt_dst, rowptr, deg,
                                                btot, zcount, N);
    scan_final_kernel<<<1, 64, 0, stream>>>(btot, boff, rowptr, zcount, fsb,
                                            flags, N, nb);
    scan_add_kernel<<<(N + 255) / 256, 256, 0, stream>>>(rowptr, boff, N);
    scatter_kernel<<<(E + 255) / 256, 256, 0, stream>>>(src_idx, dst_idx, rowptr,
                                                        cursor, esrc, E);
    dst_agg_kernel<<<(N + 3) / 4, 256, 0, stream>>>(kv, qt, h, inv_norm,
                                                    rowptr, esrc, flags, agg, N);
    out_ln_kernel<<<(N + 63) / 64, 256, 0, stream>>>(agg, WaT, ba, ln_g, ln_b,
                                                     deg, out, gcpart, N);
    gc_final_kernel<<<1, D, 0, stream>>>(gcpart, flags, gc);
    fixup_kernel<<<(N + 255) / 256, 256, 0, stream>>>(h, deg, gc, out, N);
}

// Round 4
// 283.687 us; speedup vs baseline: 1.0316x; 1.0316x over previous
//
#include <hip/hip_runtime.h>

#define D 128
#define NH 4
#define DKH 32

typedef __attribute__((ext_vector_type(8))) short short8;
typedef __attribute__((ext_vector_type(4))) float floatx4;

__device__ __forceinline__ float bf2f(unsigned int u) {
    return __uint_as_float((u & 0xffffu) << 16);
}
__device__ __forceinline__ float bf2f_hi(unsigned int u) {
    return __uint_as_float(u & 0xffff0000u);
}
__device__ __forceinline__ unsigned short f2bf(float f) {
    unsigned int x = __float_as_uint(f);
    x += 0x7fffu + ((x >> 16) & 1u);
    return (unsigned short)(x >> 16);
}

// ---------------------------------------------------------------------------
// Fold rel_{k,q,v} into W,b -> WpT (bf16 transposed); w==3 transposes Wa.
// ---------------------------------------------------------------------------
__global__ void prep_weights_kernel(
    const float* __restrict__ Wk, const float* __restrict__ bk,
    const float* __restrict__ Wq, const float* __restrict__ bq,
    const float* __restrict__ Wv, const float* __restrict__ bv,
    const float* __restrict__ rk, const float* __restrict__ rq,
    const float* __restrict__ rv, const float* __restrict__ Wa,
    unsigned short* __restrict__ WpT, unsigned short* __restrict__ WaT,
    float* __restrict__ bp)
{
    int w = blockIdx.y;
    int j = threadIdx.x;            // output column 0..127
    int i = blockIdx.x;
    if (w == 3) {
        if (i < D) WaT[(size_t)j * D + i] = f2bf(Wa[(size_t)i * D + j]);
        return;
    }
    const float* W   = (w == 0) ? Wk : (w == 1) ? Wq : Wv;
    const float* b   = (w == 0) ? bk : (w == 1) ? bq : bv;
    const float* rel = (w == 0) ? rk : (w == 1) ? rq : rv;
    int h = j >> 5, f = j & 31;
    float acc = 0.f;
    if (i < D) {
        for (int dd = 0; dd < DKH; dd++)
            acc += W[i * D + h * DKH + dd] * rel[h * 1024 + dd * DKH + f];
        WpT[((size_t)(w * D + j)) * D + i] = f2bf(acc);
    } else {
        for (int dd = 0; dd < DKH; dd++)
            acc += b[h * DKH + dd] * rel[h * 1024 + dd * DKH + f];
        bp[w * D + j] = acc;
    }
}

// ---------------------------------------------------------------------------
// MFMA GEMM: [qt | kv] = h @ W'{k,q,v} + b', plus fused row norms.
// 64 rows/block, 8 waves, wave-per-t-slice (r2 win: weights loaded once,
// zero cross-wave redundancy, pinned above staging).  Direct global stores.
// ---------------------------------------------------------------------------
#define ASTR 136
__global__ __launch_bounds__(512) void gemm_mfma_kernel(
    const float* __restrict__ h, const unsigned short* __restrict__ WpT,
    const float* __restrict__ bp,
    unsigned short* __restrict__ qt, unsigned int* __restrict__ kv,
    float* __restrict__ inv_norm, int N)
{
    __shared__ unsigned short hA[64 * ASTR];   // 17.4 KB

    int row0 = blockIdx.x * 64;
    int tid = threadIdx.x;
    int lane = tid & 63, w = tid >> 6;
    int m = lane & 15, quad = lane >> 4;

    // --- this wave's 12 weight fragments (t-slice = w), issued up front ----
    const unsigned short* kb = WpT + (size_t)(w * 16 + m) * D + quad * 8;
    const unsigned short* qb = kb + (size_t)D * D;
    const unsigned short* vb = kb + (size_t)2 * D * D;
    short8 k0 = *(const short8*)(kb);      short8 k1 = *(const short8*)(kb + 32);
    short8 k2 = *(const short8*)(kb + 64); short8 k3 = *(const short8*)(kb + 96);
    short8 q0 = *(const short8*)(qb);      short8 q1 = *(const short8*)(qb + 32);
    short8 q2 = *(const short8*)(qb + 64); short8 q3 = *(const short8*)(qb + 96);
    short8 v0 = *(const short8*)(vb);      short8 v1 = *(const short8*)(vb + 32);
    short8 v2 = *(const short8*)(vb + 64); short8 v3 = *(const short8*)(vb + 96);
    int j = w * 16 + m;
    float bkv = bp[j], bqv = bp[D + j], bvv = bp[2 * D + j];
    __builtin_amdgcn_sched_barrier(0);   // pin the loads above the staging

    // --- stage h tile into LDS as bf16 -------------------------------------
    for (int i = tid; i < 64 * 32; i += 512) {
        int r = i >> 5, c4 = (i & 31) << 2;
        int n = row0 + r;
        float4 v = make_float4(0.f, 0.f, 0.f, 0.f);
        if (n < N) v = *(const float4*)(h + (size_t)n * D + c4);
        ushort4 bv4;
        bv4.x = f2bf(v.x); bv4.y = f2bf(v.y); bv4.z = f2bf(v.z); bv4.w = f2bf(v.w);
        *(ushort4*)&hA[r * ASTR + c4] = bv4;
    }
    __syncthreads();   // the only barrier; hA stays live to kernel end

    unsigned int* qtu = (unsigned int*)qt;

#pragma unroll
    for (int tile = 0; tile < 4; tile++) {
        const unsigned short* ab = &hA[(tile * 16 + m) * ASTR + quad * 8];
        short8 a0 = *(const short8*)(ab);
        short8 a1 = *(const short8*)(ab + 32);
        short8 a2 = *(const short8*)(ab + 64);
        short8 a3 = *(const short8*)(ab + 96);
        floatx4 aK = (floatx4){0.f, 0.f, 0.f, 0.f};
        floatx4 aQ = (floatx4){0.f, 0.f, 0.f, 0.f};
        floatx4 aV = (floatx4){0.f, 0.f, 0.f, 0.f};
        aK = __builtin_amdgcn_mfma_f32_16x16x32_bf16(a0, k0, aK, 0, 0, 0);
        aQ = __builtin_amdgcn_mfma_f32_16x16x32_bf16(a0, q0, aQ, 0, 0, 0);
        aV = __builtin_amdgcn_mfma_f32_16x16x32_bf16(a0, v0, aV, 0, 0, 0);
        aK = __builtin_amdgcn_mfma_f32_16x16x32_bf16(a1, k1, aK, 0, 0, 0);
        aQ = __builtin_amdgcn_mfma_f32_16x16x32_bf16(a1, q1, aQ, 0, 0, 0);
        aV = __builtin_amdgcn_mfma_f32_16x16x32_bf16(a1, v1, aV, 0, 0, 0);
        aK = __builtin_amdgcn_mfma_f32_16x16x32_bf16(a2, k2, aK, 0, 0, 0);
        aQ = __builtin_amdgcn_mfma_f32_16x16x32_bf16(a2, q2, aQ, 0, 0, 0);
        aV = __builtin_amdgcn_mfma_f32_16x16x32_bf16(a2, v2, aV, 0, 0, 0);
        aK = __builtin_amdgcn_mfma_f32_16x16x32_bf16(a3, k3, aK, 0, 0, 0);
        aQ = __builtin_amdgcn_mfma_f32_16x16x32_bf16(a3, q3, aQ, 0, 0, 0);
        aV = __builtin_amdgcn_mfma_f32_16x16x32_bf16(a3, v3, aV, 0, 0, 0);
#pragma unroll
        for (int r = 0; r < 4; r++) {
            int row = tile * 16 + quad * 4 + r;
            int n = row0 + row;
            float kval = aK[r] + bkv;
            float qval = aQ[r] + bqv;
            float vval = aV[r] + bvv;
            float qpart = __shfl_xor(qval, 1);
            unsigned int kvp = (unsigned int)f2bf(kval)
                             | ((unsigned int)f2bf(vval) << 16);
            unsigned int qp  = (unsigned int)f2bf(qval)
                             | ((unsigned int)f2bf(qpart) << 16);
            if (n < N) {
                kv[(size_t)n * D + w * 16 + m] = kvp;            // 4x64B segs
                if (!(m & 1))
                    qtu[(size_t)n * 64 + w * 8 + (m >> 1)] = qp; // 4x32B segs
            }
        }
    }

    // --- row norms: waves 0..3 own rows w*16..w*16+15 (hA still live) ------
    if (w < 4) {
        for (int rr = 0; rr < 16; rr += 4) {
            float s0, s1, s2, s3;
            {
                unsigned int u0 = *(const unsigned int*)&hA[(w * 16 + rr + 0) * ASTR + lane * 2];
                unsigned int u1 = *(const unsigned int*)&hA[(w * 16 + rr + 1) * ASTR + lane * 2];
                unsigned int u2 = *(const unsigned int*)&hA[(w * 16 + rr + 2) * ASTR + lane * 2];
                unsigned int u3 = *(const unsigned int*)&hA[(w * 16 + rr + 3) * ASTR + lane * 2];
                float a, b;
                a = bf2f(u0); b = bf2f_hi(u0); s0 = a * a + b * b;
                a = bf2f(u1); b = bf2f_hi(u1); s1 = a * a + b * b;
                a = bf2f(u2); b = bf2f_hi(u2); s2 = a * a + b * b;
                a = bf2f(u3); b = bf2f_hi(u3); s3 = a * a + b * b;
            }
#pragma unroll
            for (int off = 1; off < 64; off <<= 1) {
                s0 += __shfl_xor(s0, off);
                s1 += __shfl_xor(s1, off);
                s2 += __shfl_xor(s2, off);
                s3 += __shfl_xor(s3, off);
            }
            if (lane < 4) {
                float sv = (lane == 0) ? s0 : (lane == 1) ? s1 : (lane == 2) ? s2 : s3;
                int n = row0 + w * 16 + rr + lane;
                if (n < N) inv_norm[n] = 1.0f / fmaxf(sqrtf(sv), 1e-12f);
            }
        }
    }
}

// ---------------------------------------------------------------------------
// Histogram: src presence via plain byte store (benign race; deg only ever
// tested != 0), dst incidence via atomicAdd (CSR sizes need exact counts).
// ---------------------------------------------------------------------------
__global__ void deg_hist_kernel(const int* __restrict__ src, const int* __restrict__ dst,
                                unsigned char* __restrict__ sflag,
                                int* __restrict__ cnt_dst, int E)
{
    int e = blockIdx.x * blockDim.x + threadIdx.x;
    if (e >= E) return;
    sflag[src[e]] = 1;
    atomicAdd(&cnt_dst[dst[e]], 1);
}

// ---------------------------------------------------------------------------
__global__ __launch_bounds__(1024) void scan_blocks_kernel(
    const unsigned char* __restrict__ sflag, const int* __restrict__ cnt_dst,
    int* __restrict__ rowptr, int* __restrict__ deg,
    int* __restrict__ btot, int* __restrict__ zcount, int N)
{
    __shared__ int wtot[16];
    __shared__ int wscan[16];
    int tid = threadIdx.x, lane = tid & 63, wv = tid >> 6;
    int i = blockIdx.x * 1024 + tid;
    int cs = 0, cd = 0;
    if (i < N) { cs = sflag[i]; cd = cnt_dst[i]; }
    int x = cd;
#pragma unroll
    for (int off = 1; off < 64; off <<= 1) {
        int y = __shfl_up(x, off);
        if (lane >= off) x += y;
    }
    if (lane == 63) wtot[wv] = x;
    __syncthreads();
    if (wv == 0) {
        int t = (lane < 16) ? wtot[lane] : 0;
#pragma unroll
        for (int off = 1; off < 16; off <<= 1) {
            int y = __shfl_up(t, off);
            if (lane >= off) t += y;
        }
        if (lane < 16) wscan[lane] = t;
    }
    __syncthreads();
    int woff = (wv == 0) ? 0 : wscan[wv - 1];
    if (i < N) {
        rowptr[i] = woff + x - cd;
        deg[i] = (cs | (cd > 0)) ? 1 : 0;   // 0/1 indicator; only ever tested != 0
    }
    if (tid == 0) btot[blockIdx.x] = wscan[15];
    int zc = (i < N && cs == 0 && cd == 0) ? 1 : 0;
#pragma unroll
    for (int off = 1; off < 64; off <<= 1) zc += __shfl_xor(zc, off);
    if (lane == 0 && zc) atomicAdd(zcount, zc);
}

// ---------------------------------------------------------------------------
__global__ void scan_final_kernel(const int* __restrict__ btot,
                                  int* __restrict__ boff, int* __restrict__ rowptr,
                                  const int* __restrict__ zcount,
                                  const float* __restrict__ fsb,
                                  float* __restrict__ flags, int N, int nb)
{
    int lane = threadIdx.x;   // 64
    int v = (lane < nb) ? btot[lane] : 0;
    int x = v;
#pragma unroll
    for (int off = 1; off < 64; off <<= 1) {
        int y = __shfl_up(x, off);
        if (lane >= off) x += y;
    }
    if (lane < nb) boff[lane] = x - v;
    if (lane == 63) rowptr[N] = x;    // grand total = E
    if (lane == 0) {
        float z = (float)zcount[0];
        float sparsity = z / (float)N;
        flags[0] = (sparsity > 0.3f) ? fsb[0] : 0.f;
        flags[1] = fmaxf((float)N - z, 1.f);
    }
}

__global__ void scan_add_kernel(int* __restrict__ rowptr,
                                const int* __restrict__ boff, int N)
{
    int i = blockIdx.x * blockDim.x + threadIdx.x;
    if (i < N) rowptr[i] += boff[i >> 10];
}

// ---------------------------------------------------------------------------
__global__ void scatter_kernel(const int* __restrict__ src, const int* __restrict__ dst,
                               const int* __restrict__ rowptr, int* __restrict__ cursor,
                               int* __restrict__ esrc, int E)
{
    int e = blockIdx.x * blockDim.x + threadIdx.x;
    if (e >= E) return;
    int d = dst[e];
    int pos = rowptr[d] + atomicAdd(&cursor[d], 1);
    esrc[pos] = src[e];
}

// ---------------------------------------------------------------------------
// Fused softmax + aggregation, gather-based, ZERO atomics.
// One wave per dst node, 32 lanes/edge, 8 edges/iter.
// r4: edge indices loaded ONCE per node into registers (one coalesced load
// of esrc[beg+lane], distributed via __shfl) -> the per-iteration dependent
// chain is shfl->gather instead of load->gather.  Memory fallback deg>64.
// ---------------------------------------------------------------------------
__global__ __launch_bounds__(256) void dst_agg_kernel(
    const unsigned int* __restrict__ kv, const unsigned short* __restrict__ qt,
    const float* __restrict__ h, const float* __restrict__ inv_norm,
    const int* __restrict__ rowptr, const int* __restrict__ esrc,
    const float* __restrict__ flags,
    unsigned int* __restrict__ agg, int N)
{
    int n = (blockIdx.x * blockDim.x + threadIdx.x) >> 6;
    int lane = threadIdx.x & 63;
    if (n >= N) return;
    int half = lane >> 5, c = lane & 31;
    int beg = rowptr[n], end = rowptr[n + 1];
    int d = end - beg;
    int myi = (lane < d) ? esrc[beg + lane] : 0;   // up to 64 edge ids, one load
    uint2 qw = *(const uint2*)(qt + (size_t)n * D + c * 4);
    float q0 = bf2f(qw.x), q1 = bf2f_hi(qw.x);
    float q2 = bf2f(qw.y), q3 = bf2f_hi(qw.y);
    float boost = flags[0];
    float hn0 = 0.f, hn1 = 0.f, hn2 = 0.f, hn3 = 0.f, innd = 0.f;
    if (boost != 0.f) {
        float4 hh = *(const float4*)(h + (size_t)n * D + c * 4);
        hn0 = hh.x; hn1 = hh.y; hn2 = hh.z; hn3 = hh.w; innd = inv_norm[n];
    }
    const float SC = 0.17677669529663687f;   // 1/sqrt(32)
    float a0 = 0.f, a1 = 0.f, a2 = 0.f, a3 = 0.f, den = 0.f;
    int dd = (d > 64) ? 64 : d;
    int p = 0;
    // ---- main: 8 edges / iteration, indices from registers ----------------
    for (; p + 7 < dd; p += 8) {
        int sA = __shfl(myi, p + half);
        int sB = __shfl(myi, p + 2 + half);
        int sC = __shfl(myi, p + 4 + half);
        int sD = __shfl(myi, p + 6 + half);
        uint4 wA = *(const uint4*)(kv + (size_t)sA * D + c * 4);
        uint4 wB = *(const uint4*)(kv + (size_t)sB * D + c * 4);
        uint4 wC = *(const uint4*)(kv + (size_t)sC * D + c * 4);
        uint4 wD = *(const uint4*)(kv + (size_t)sD * D + c * 4);
        float dA = q0 * bf2f(wA.x) + q1 * bf2f(wA.y)
                 + q2 * bf2f(wA.z) + q3 * bf2f(wA.w);
        float dB = q0 * bf2f(wB.x) + q1 * bf2f(wB.y)
                 + q2 * bf2f(wB.z) + q3 * bf2f(wB.w);
        float dC = q0 * bf2f(wC.x) + q1 * bf2f(wC.y)
                 + q2 * bf2f(wC.z) + q3 * bf2f(wC.w);
        float dD = q0 * bf2f(wD.x) + q1 * bf2f(wD.y)
                 + q2 * bf2f(wD.z) + q3 * bf2f(wD.w);
        dA += __shfl_xor(dA, 1);  dB += __shfl_xor(dB, 1);
        dC += __shfl_xor(dC, 1);  dD += __shfl_xor(dD, 1);
        dA += __shfl_xor(dA, 2);  dB += __shfl_xor(dB, 2);
        dC += __shfl_xor(dC, 2);  dD += __shfl_xor(dD, 2);
        dA += __shfl_xor(dA, 4);  dB += __shfl_xor(dB, 4);
        dC += __shfl_xor(dC, 4);  dD += __shfl_xor(dD, 4);
        float attA = dA * SC, attB = dB * SC;
        float attC = dC * SC, attD = dD * SC;
        if (boost != 0.f) {
            float4 xA = *(const float4*)(h + (size_t)sA * D + c * 4);
            float4 xB = *(const float4*)(h + (size_t)sB * D + c * 4);
            float4 xC = *(const float4*)(h + (size_t)sC * D + c * 4);
            float4 xD = *(const float4*)(h + (size_t)sD * D + c * 4);
            float fA = hn0 * xA.x + hn1 * xA.y + hn2 * xA.z + hn3 * xA.w;
            float fB = hn0 * xB.x + hn1 * xB.y + hn2 * xB.z + hn3 * xB.w;
            float fC = hn0 * xC.x + hn1 * xC.y + hn2 * xC.z + hn3 * xC.w;
            float fD = hn0 * xD.x + hn1 * xD.y + hn2 * xD.z + hn3 * xD.w;
#pragma unroll
            for (int off = 1; off < 32; off <<= 1) {
                fA += __shfl_xor(fA, off);
                fB += __shfl_xor(fB, off);
                fC += __shfl_xor(fC, off);
                fD += __shfl_xor(fD, off);
            }
            attA += fA * inv_norm[sA] * innd * boost;
            attB += fB * inv_norm[sB] * innd * boost;
            attC += fC * inv_norm[sC] * innd * boost;
            attD += fD * inv_norm[sD] * innd * boost;
        }
        attA = fminf(fmaxf(attA, -60.f), 60.f);
        attB = fminf(fmaxf(attB, -60.f), 60.f);
        attC = fminf(fmaxf(attC, -60.f), 60.f);
        attD = fminf(fmaxf(attD, -60.f), 60.f);
        float pA = __expf(attA), pB = __expf(attB);
        float pC = __expf(attC), pD = __expf(attD);
        den += (pA + pB) + (pC + pD);
        a0 += pA * bf2f_hi(wA.x) + pB * bf2f_hi(wB.x)
            + pC * bf2f_hi(wC.x) + pD * bf2f_hi(wD.x);
        a1 += pA * bf2f_hi(wA.y) + pB * bf2f_hi(wB.y)
            + pC * bf2f_hi(wC.y) + pD * bf2f_hi(wD.y);
        a2 += pA * bf2f_hi(wA.z) + pB * bf2f_hi(wB.z)
            + pC * bf2f_hi(wC.z) + pD * bf2f_hi(wD.z);
        a3 += pA * bf2f_hi(wA.w) + pB * bf2f_hi(wB.w)
            + pC * bf2f_hi(wC.w) + pD * bf2f_hi(wD.w);
    }
    // ---- register tails: 2 edges / 1 edge ---------------------------------
    for (; p + 1 < dd; p += 2) {
        int sA = __shfl(myi, p + half);
        uint4 wA = *(const uint4*)(kv + (size_t)sA * D + c * 4);
        float dA = q0 * bf2f(wA.x) + q1 * bf2f(wA.y)
                 + q2 * bf2f(wA.z) + q3 * bf2f(wA.w);
        dA += __shfl_xor(dA, 1);
        dA += __shfl_xor(dA, 2);
        dA += __shfl_xor(dA, 4);
        float attA = dA * SC;
        if (boost != 0.f) {
            float4 xA = *(const float4*)(h + (size_t)sA * D + c * 4);
            float fA = hn0 * xA.x + hn1 * xA.y + hn2 * xA.z + hn3 * xA.w;
#pragma unroll
            for (int off = 1; off < 32; off <<= 1) fA += __shfl_xor(fA, off);
            attA += fA * inv_norm[sA] * innd * boost;
        }
        attA = fminf(fmaxf(attA, -60.f), 60.f);
        float pA = __expf(attA);
        den += pA;
        a0 += pA * bf2f_hi(wA.x);
        a1 += pA * bf2f_hi(wA.y);
        a2 += pA * bf2f_hi(wA.z);
        a3 += pA * bf2f_hi(wA.w);
    }
    if (p < dd && half == 0) {
        int sA = __shfl(myi, p);
        uint4 wA = *(const uint4*)(kv + (size_t)sA * D + c * 4);
        float dA = q0 * bf2f(wA.x) + q1 * bf2f(wA.y)
                 + q2 * bf2f(wA.z) + q3 * bf2f(wA.w);
        dA += __shfl_xor(dA, 1);
        dA += __shfl_xor(dA, 2);
        dA += __shfl_xor(dA, 4);
        float attA = dA * SC;
        if (boost != 0.f) {
            float4 xA = *(const float4*)(h + (size_t)sA * D + c * 4);
            float fA = hn0 * xA.x + hn1 * xA.y + hn2 * xA.z + hn3 * xA.w;
#pragma unroll
            for (int off = 1; off < 32; off <<= 1) fA += __shfl_xor(fA, off);
            attA += fA * inv_norm[sA] * innd * boost;
        }
        attA = fminf(fmaxf(attA, -60.f), 60.f);
        float pA = __expf(attA);
        den += pA;
        a0 += pA * bf2f_hi(wA.x);
        a1 += pA * bf2f_hi(wA.y);
        a2 += pA * bf2f_hi(wA.z);
        a3 += pA * bf2f_hi(wA.w);
    }
    if (p < dd) p = dd;
    // ---- memory fallback for deg > 64 (practically never taken) -----------
    for (; p + 1 < d; p += 2) {
        int sA = esrc[beg + p + half];
        uint4 wA = *(const uint4*)(kv + (size_t)sA * D + c * 4);
        float dA = q0 * bf2f(wA.x) + q1 * bf2f(wA.y)
                 + q2 * bf2f(wA.z) + q3 * bf2f(wA.w);
        dA += __shfl_xor(dA, 1);
        dA += __shfl_xor(dA, 2);
        dA += __shfl_xor(dA, 4);
        float attA = dA * SC;
        if (boost != 0.f) {
            float4 xA = *(const float4*)(h + (size_t)sA * D + c * 4);
            float fA = hn0 * xA.x + hn1 * xA.y + hn2 * xA.z + hn3 * xA.w;
#pragma unroll
            for (int off = 1; off < 32; off <<= 1) fA += __shfl_xor(fA, off);
            attA += fA * inv_norm[sA] * innd * boost;
        }
        attA = fminf(fmaxf(attA, -60.f), 60.f);
        float pA = __expf(attA);
        den += pA;
        a0 += pA * bf2f_hi(wA.x);
        a1 += pA * bf2f_hi(wA.y);
        a2 += pA * bf2f_hi(wA.z);
        a3 += pA * bf2f_hi(wA.w);
    }
    if (p < d && half == 0) {
        int sA = esrc[beg + p];
        uint4 wA = *(const uint4*)(kv + (size_t)sA * D + c * 4);
        float dA = q0 * bf2f(wA.x) + q1 * bf2f(wA.y)
                 + q2 * bf2f(wA.z) + q3 * bf2f(wA.w);
        dA += __shfl_xor(dA, 1);
        dA += __shfl_xor(dA, 2);
        dA += __shfl_xor(dA, 4);
        float attA = dA * SC;
        if (boost != 0.f) {
            float4 xA = *(const float4*)(h + (size_t)sA * D + c * 4);
            float fA = hn0 * xA.x + hn1 * xA.y + hn2 * xA.z + hn3 * xA.w;
#pragma unroll
            for (int off = 1; off < 32; off <<= 1) fA += __shfl_xor(fA, off);
            attA += fA * inv_norm[sA] * innd * boost;
        }
        attA = fminf(fmaxf(attA, -60.f), 60.f);
        float pA = __expf(attA);
        den += pA;
        a0 += pA * bf2f_hi(wA.x);
        a1 += pA * bf2f_hi(wA.y);
        a2 += pA * bf2f_hi(wA.z);
        a3 += pA * bf2f_hi(wA.w);
    }
    den += __shfl_xor(den, 32);
    a0  += __shfl_xor(a0, 32);
    a1  += __shfl_xor(a1, 32);
    a2  += __shfl_xor(a2, 32);
    a3  += __shfl_xor(a3, 32);
    if (half == 0) {
        float r = 1.0f / fmaxf(den, 1e-38f);
        uint2 o;
        o.x = (unsigned int)f2bf(a0 * r) | ((unsigned int)f2bf(a1 * r) << 16);
        o.y = (unsigned int)f2bf(a2 * r) | ((unsigned int)f2bf(a3 * r) << 16);
        *(uint2*)(agg + (size_t)n * (D / 2) + c * 2) = o;
    }
}

// ---------------------------------------------------------------------------
// out = LN(agg @ Wa + ba) via MFMA.  r4 restructure (mirrors r2 gemm win):
// 64 rows/block, 512 threads, 8 waves, wave-per-column-slice.  Wave w owns
// output cols w*16..+15 for all 64 rows; its 4 Wa fragments + bias load ONCE
// at kernel top (zero cross-wave redundancy), pinned via sched_barrier.
// Pre-LN bf16 goes to a separate os LDS buffer (transpose for LN); LN phase
// re-owns rows 8/wave.  LDS 34.8 KB.
// ---------------------------------------------------------------------------
__global__ __launch_bounds__(512) void out_ln_kernel(
    const unsigned int* __restrict__ agg,      // packed bf16 pairs
    const unsigned short* __restrict__ WaT, const float* __restrict__ ba,
    const float* __restrict__ ln_g, const float* __restrict__ ln_b,
    const int* __restrict__ deg, float* __restrict__ out,
    float* __restrict__ gcpart, int N)
{
    __shared__ unsigned short aB[64 * ASTR];   // 17.4 KB staged agg
    __shared__ unsigned short os[64 * ASTR];   // 17.4 KB pre-LN values
    int row0 = blockIdx.x * 64;
    int tid = threadIdx.x;
    int lane = tid & 63, w = tid >> 6;
    int m = lane & 15, quad = lane >> 4;

    // --- this wave's 4 Wa fragments (col-slice = w), issued up front -------
    int j = w * 16 + m;
    const unsigned short* wb = WaT + (size_t)j * D + quad * 8;
    short8 B0 = *(const short8*)(wb);
    short8 B1 = *(const short8*)(wb + 32);
    short8 B2 = *(const short8*)(wb + 64);
    short8 B3 = *(const short8*)(wb + 96);
    float bj = ba[j];
    __builtin_amdgcn_sched_barrier(0);

    // --- stage agg into LDS ------------------------------------------------
    for (int i = tid; i < 64 * 16; i += 512) {
        int r = i >> 4, c8 = (i & 15) << 3;
        int n = row0 + r;
        uint4 v = make_uint4(0u, 0u, 0u, 0u);
        if (n < N) v = *(const uint4*)(agg + (size_t)n * (D / 2) + (c8 >> 1));
        *(uint4*)&aB[r * ASTR + c8] = v;
    }
    __syncthreads();

#pragma unroll
    for (int tile = 0; tile < 4; tile++) {
        const unsigned short* ab = &aB[(tile * 16 + m) * ASTR + quad * 8];
        short8 a0 = *(const short8*)(ab);
        short8 a1 = *(const short8*)(ab + 32);
        short8 a2 = *(const short8*)(ab + 64);
        short8 a3 = *(const short8*)(ab + 96);
        floatx4 acc = (floatx4){0.f, 0.f, 0.f, 0.f};
        acc = __builtin_amdgcn_mfma_f32_16x16x32_bf16(a0, B0, acc, 0, 0, 0);
        acc = __builtin_amdgcn_mfma_f32_16x16x32_bf16(a1, B1, acc, 0, 0, 0);
        acc = __builtin_amdgcn_mfma_f32_16x16x32_bf16(a2, B2, acc, 0, 0, 0);
        acc = __builtin_amdgcn_mfma_f32_16x16x32_bf16(a3, B3, acc, 0, 0, 0);
#pragma unroll
        for (int r = 0; r < 4; r++)
            os[(tile * 16 + quad * 4 + r) * ASTR + j] = f2bf(acc[r] + bj);
    }
    __syncthreads();

    // --- LN phase: wave w owns rows w*8 .. w*8+7 ---------------------------
    int j2 = lane * 2;
    float g0 = ln_g[j2], g1 = ln_g[j2 + 1];
    float b0 = ln_b[j2], b1 = ln_b[j2 + 1];
    float gcs0 = 0.f, gcs1 = 0.f;
    for (int rr = 0; rr < 8; rr++) {
        int r = w * 8 + rr;
        int n = row0 + r;
        if (n >= N) break;
        unsigned int u = *(const unsigned int*)&os[r * ASTR + j2];
        float x0 = bf2f(u), x1 = bf2f_hi(u);
        float s = x0 + x1, s2 = x0 * x0 + x1 * x1;
#pragma unroll
        for (int off = 1; off < 64; off <<= 1) {
            s  += __shfl_xor(s, off);
            s2 += __shfl_xor(s2, off);
        }
        float mu = s * (1.f / 128.f);
        float var = s2 * (1.f / 128.f) - mu * mu;
        float rstd = rsqrtf(fmaxf(var, 0.f) + 1e-5f);
        float y0 = (x0 - mu) * rstd * g0 + b0;
        float y1 = (x1 - mu) * rstd * g1 + b1;
        *(float2*)(out + (size_t)n * D + j2) = make_float2(y0, y1);
        if (deg[n] != 0) { gcs0 += y0; gcs1 += y1; }
    }
    int slot = blockIdx.x & 63;
    if (gcs0 != 0.f || gcs1 != 0.f) {
        atomicAdd(&gcpart[slot * D + j2],     gcs0);
        atomicAdd(&gcpart[slot * D + j2 + 1], gcs1);
    }
}

__global__ void gc_final_kernel(const float* __restrict__ gcpart,
                                const float* __restrict__ flags,
                                float* __restrict__ gc)
{
    int j = threadIdx.x;  // 128
    float s = 0.f;
    for (int i = 0; i < 64; i++) s += gcpart[i * D + j];
    gc[j] = s / flags[1];
}

// ---------------------------------------------------------------------------
__global__ void fixup_kernel(const float* __restrict__ h,
                             const int* __restrict__ deg,
                             const float* __restrict__ gc,
                             float* __restrict__ out, int N)
{
    int n = blockIdx.x * blockDim.x + threadIdx.x;
    if (n >= N) return;
    if (deg[n] != 0) return;
    for (int j = 0; j < D; j += 4) {
        float4 hv = *(const float4*)(h + (size_t)n * D + j);
        float4 gv = *(const float4*)(gc + j);
        float4 o;
        o.x = 0.9f * hv.x + 0.1f * gv.x;
        o.y = 0.9f * hv.y + 0.1f * gv.y;
        o.z = 0.9f * hv.z + 0.1f * gv.z;
        o.w = 0.9f * hv.w + 0.1f * gv.w;
        *(float4*)(out + (size_t)n * D + j) = o;
    }
}

// ---------------------------------------------------------------------------
extern "C" void kernel_launch(void* const* d_in, const int* in_sizes, int n_in,
                              void* d_out, int out_size, void* d_ws, size_t ws_size,
                              hipStream_t stream)
{
    const float* h       = (const float*)d_in[0];
    const int* src_idx   = (const int*)d_in[1];
    const int* dst_idx   = (const int*)d_in[2];
    const float* Wk      = (const float*)d_in[3];
    const float* bk      = (const float*)d_in[4];
    const float* Wq      = (const float*)d_in[5];
    const float* bq      = (const float*)d_in[6];
    const float* Wv      = (const float*)d_in[7];
    const float* bv      = (const float*)d_in[8];
    const float* rk      = (const float*)d_in[9];
    const float* rq      = (const float*)d_in[10];
    const float* rv      = (const float*)d_in[11];
    const float* Wa      = (const float*)d_in[12];
    const float* ba      = (const float*)d_in[13];
    const float* ln_g    = (const float*)d_in[14];
    const float* ln_b    = (const float*)d_in[15];
    const float* fsb     = (const float*)d_in[16];
    float* out           = (float*)d_out;

    int N = in_sizes[0] / D;
    int E = in_sizes[1];
    int nb = (N + 1023) >> 10;   // scan blocks (<= 64)

    // ---- workspace: small control buffers first ---------------------------
    char* p = (char*)d_ws;
    auto alloc = [&](size_t bytes) { char* q = p; p += (bytes + 15) & ~(size_t)15; return q; };

    unsigned short* WpT = (unsigned short*)alloc(3 * D * D * 2);
    unsigned short* WaT = (unsigned short*)alloc(D * D * 2);
    float* bp       = (float*)alloc(3 * D * 4);
    float* gc       = (float*)alloc(D * 4);
    float* flags    = (float*)alloc(2 * 4);
    int*   btot     = (int*)alloc(64 * 4);
    int*   boff     = (int*)alloc(64 * 4);
    float* inv_norm = (float*)alloc((size_t)N * 4);
    int*   rowptr   = (int*)alloc(((size_t)N + 1) * 4);
    int*   deg      = (int*)alloc((size_t)N * 4);
    // zero region: sflag, cnt_dst, cursor, zcount, gcpart (contiguous)
    char* z1 = p;
    unsigned char* sflag = (unsigned char*)alloc((size_t)N);
    int*   cnt_dst = (int*)alloc((size_t)N * 4);
    int*   cursor  = (int*)alloc((size_t)N * 4);
    int*   zcount  = (int*)alloc(4);
    float* gcpart  = (float*)alloc(64 * D * 4);
    size_t z1_bytes = (size_t)(p - z1);
    // big arrays
    unsigned short* qt = (unsigned short*)alloc((size_t)N * D * 2);
    unsigned int*   kv = (unsigned int*)alloc((size_t)N * D * 4);
    int*   esrc        = (int*)alloc((size_t)E * 4);
    unsigned int* agg  = (unsigned int*)alloc((size_t)N * D * 2);

    hipMemsetAsync(z1, 0, z1_bytes, stream);

    prep_weights_kernel<<<dim3(129, 4), 128, 0, stream>>>(Wk, bk, Wq, bq, Wv, bv,
                                                          rk, rq, rv, Wa,
                                                          WpT, WaT, bp);
    gemm_mfma_kernel<<<(N + 63) / 64, 512, 0, stream>>>(h, WpT, bp, qt, kv,
                                                        inv_norm, N);
    deg_hist_kernel<<<(E + 255) / 256, 256, 0, stream>>>(src_idx, dst_idx,
                                                         sflag, cnt_dst, E);
    scan_blocks_kernel<<<nb, 1024, 0, stream>>>(sflag, cnt_dst, rowptr, deg,
                                                btot, zcount, N);
    scan_final_kernel<<<1, 64, 0, stream>>>(btot, boff, rowptr, zcount, fsb,
                                            flags, N, nb);
    scan_add_kernel<<<(N + 255) / 256, 256, 0, stream>>>(rowptr, boff, N);
    scatter_kernel<<<(E + 255) / 256, 256, 0, stream>>>(src_idx, dst_idx, rowptr,
                                                        cursor, esrc, E);
    dst_agg_kernel<<<(N + 3) / 4, 256, 0, stream>>>(kv, qt, h, inv_norm,
                                                    rowptr, esrc, flags, agg, N);
    out_ln_kernel<<<(N + 63) / 64, 512, 0, stream>>>(agg, WaT, ba, ln_g, ln_b,
                                                     deg, out, gcpart, N);
    gc_final_kernel<<<1, D, 0, stream>>>(gcpart, flags, gc);
    fixup_kernel<<<(N + 255) / 256, 256, 0, stream>>>(h, deg, gc, out, N);
}

// Round 5
// 267.437 us; speedup vs baseline: 1.0943x; 1.0608x over previous
//
#include <hip/hip_runtime.h>

#define D 128
#define NH 4
#define DKH 32

typedef __attribute__((ext_vector_type(8))) short short8;
typedef __attribute__((ext_vector_type(4))) float floatx4;

__device__ __forceinline__ float bf2f(unsigned int u) {
    return __uint_as_float((u & 0xffffu) << 16);
}
__device__ __forceinline__ float bf2f_hi(unsigned int u) {
    return __uint_as_float(u & 0xffff0000u);
}
__device__ __forceinline__ unsigned short f2bf(float f) {
    unsigned int x = __float_as_uint(f);
    x += 0x7fffu + ((x >> 16) & 1u);
    return (unsigned short)(x >> 16);
}

// ---------------------------------------------------------------------------
// Fold rel_{k,q,v} into W,b -> WpT (bf16 transposed); w==3 transposes Wa.
// ---------------------------------------------------------------------------
__global__ void prep_weights_kernel(
    const float* __restrict__ Wk, const float* __restrict__ bk,
    const float* __restrict__ Wq, const float* __restrict__ bq,
    const float* __restrict__ Wv, const float* __restrict__ bv,
    const float* __restrict__ rk, const float* __restrict__ rq,
    const float* __restrict__ rv, const float* __restrict__ Wa,
    unsigned short* __restrict__ WpT, unsigned short* __restrict__ WaT,
    float* __restrict__ bp)
{
    int w = blockIdx.y;
    int j = threadIdx.x;            // output column 0..127
    int i = blockIdx.x;
    if (w == 3) {
        if (i < D) WaT[(size_t)j * D + i] = f2bf(Wa[(size_t)i * D + j]);
        return;
    }
    const float* W   = (w == 0) ? Wk : (w == 1) ? Wq : Wv;
    const float* b   = (w == 0) ? bk : (w == 1) ? bq : bv;
    const float* rel = (w == 0) ? rk : (w == 1) ? rq : rv;
    int h = j >> 5, f = j & 31;
    float acc = 0.f;
    if (i < D) {
        for (int dd = 0; dd < DKH; dd++)
            acc += W[i * D + h * DKH + dd] * rel[h * 1024 + dd * DKH + f];
        WpT[((size_t)(w * D + j)) * D + i] = f2bf(acc);
    } else {
        for (int dd = 0; dd < DKH; dd++)
            acc += b[h * DKH + dd] * rel[h * 1024 + dd * DKH + f];
        bp[w * D + j] = acc;
    }
}

// ---------------------------------------------------------------------------
// MERGED: MFMA GEMM ([qt|kv] = h @ W' + b' + row norms) for blocks < nG,
// edge histogram (sflag/cnt_dst) for blocks >= nG.  r5: the atomic-bound
// histogram fills the latency-bound gemm's idle issue slots and one launch
// gap disappears.  Gemm part = r2 structure (wave-per-t-slice, weights
// loaded once, pinned above staging; direct global stores; one barrier).
// ---------------------------------------------------------------------------
#define ASTR 136
__global__ __launch_bounds__(512) void gemm_hist_kernel(
    const float* __restrict__ h, const unsigned short* __restrict__ WpT,
    const float* __restrict__ bp,
    unsigned short* __restrict__ qt, unsigned int* __restrict__ kv,
    float* __restrict__ inv_norm,
    const int* __restrict__ src, const int* __restrict__ dst,
    unsigned char* __restrict__ sflag, int* __restrict__ cnt_dst,
    int N, int E, int nG)
{
    __shared__ unsigned short hA[64 * ASTR];   // 17.4 KB (gemm blocks only)

    int tid = threadIdx.x;
    if ((int)blockIdx.x >= nG) {
        int e = ((int)blockIdx.x - nG) * 512 + tid;
        if (e < E) {
            sflag[src[e]] = 1;                 // benign race; tested != 0 only
            atomicAdd(&cnt_dst[dst[e]], 1);    // exact counts for CSR
        }
        return;
    }

    int row0 = blockIdx.x * 64;
    int lane = tid & 63, w = tid >> 6;
    int m = lane & 15, quad = lane >> 4;

    // --- this wave's 12 weight fragments (t-slice = w), issued up front ----
    const unsigned short* kb = WpT + (size_t)(w * 16 + m) * D + quad * 8;
    const unsigned short* qb = kb + (size_t)D * D;
    const unsigned short* vb = kb + (size_t)2 * D * D;
    short8 k0 = *(const short8*)(kb);      short8 k1 = *(const short8*)(kb + 32);
    short8 k2 = *(const short8*)(kb + 64); short8 k3 = *(const short8*)(kb + 96);
    short8 q0 = *(const short8*)(qb);      short8 q1 = *(const short8*)(qb + 32);
    short8 q2 = *(const short8*)(qb + 64); short8 q3 = *(const short8*)(qb + 96);
    short8 v0 = *(const short8*)(vb);      short8 v1 = *(const short8*)(vb + 32);
    short8 v2 = *(const short8*)(vb + 64); short8 v3 = *(const short8*)(vb + 96);
    int j = w * 16 + m;
    float bkv = bp[j], bqv = bp[D + j], bvv = bp[2 * D + j];
    __builtin_amdgcn_sched_barrier(0);   // pin the loads above the staging

    // --- stage h tile into LDS as bf16 -------------------------------------
    for (int i = tid; i < 64 * 32; i += 512) {
        int r = i >> 5, c4 = (i & 31) << 2;
        int n = row0 + r;
        float4 v = make_float4(0.f, 0.f, 0.f, 0.f);
        if (n < N) v = *(const float4*)(h + (size_t)n * D + c4);
        ushort4 bv4;
        bv4.x = f2bf(v.x); bv4.y = f2bf(v.y); bv4.z = f2bf(v.z); bv4.w = f2bf(v.w);
        *(ushort4*)&hA[r * ASTR + c4] = bv4;
    }
    __syncthreads();   // the only barrier; hA stays live to kernel end

    unsigned int* qtu = (unsigned int*)qt;

#pragma unroll
    for (int tile = 0; tile < 4; tile++) {
        const unsigned short* ab = &hA[(tile * 16 + m) * ASTR + quad * 8];
        short8 a0 = *(const short8*)(ab);
        short8 a1 = *(const short8*)(ab + 32);
        short8 a2 = *(const short8*)(ab + 64);
        short8 a3 = *(const short8*)(ab + 96);
        floatx4 aK = (floatx4){0.f, 0.f, 0.f, 0.f};
        floatx4 aQ = (floatx4){0.f, 0.f, 0.f, 0.f};
        floatx4 aV = (floatx4){0.f, 0.f, 0.f, 0.f};
        aK = __builtin_amdgcn_mfma_f32_16x16x32_bf16(a0, k0, aK, 0, 0, 0);
        aQ = __builtin_amdgcn_mfma_f32_16x16x32_bf16(a0, q0, aQ, 0, 0, 0);
        aV = __builtin_amdgcn_mfma_f32_16x16x32_bf16(a0, v0, aV, 0, 0, 0);
        aK = __builtin_amdgcn_mfma_f32_16x16x32_bf16(a1, k1, aK, 0, 0, 0);
        aQ = __builtin_amdgcn_mfma_f32_16x16x32_bf16(a1, q1, aQ, 0, 0, 0);
        aV = __builtin_amdgcn_mfma_f32_16x16x32_bf16(a1, v1, aV, 0, 0, 0);
        aK = __builtin_amdgcn_mfma_f32_16x16x32_bf16(a2, k2, aK, 0, 0, 0);
        aQ = __builtin_amdgcn_mfma_f32_16x16x32_bf16(a2, q2, aQ, 0, 0, 0);
        aV = __builtin_amdgcn_mfma_f32_16x16x32_bf16(a2, v2, aV, 0, 0, 0);
        aK = __builtin_amdgcn_mfma_f32_16x16x32_bf16(a3, k3, aK, 0, 0, 0);
        aQ = __builtin_amdgcn_mfma_f32_16x16x32_bf16(a3, q3, aQ, 0, 0, 0);
        aV = __builtin_amdgcn_mfma_f32_16x16x32_bf16(a3, v3, aV, 0, 0, 0);
#pragma unroll
        for (int r = 0; r < 4; r++) {
            int row = tile * 16 + quad * 4 + r;
            int n = row0 + row;
            float kval = aK[r] + bkv;
            float qval = aQ[r] + bqv;
            float vval = aV[r] + bvv;
            float qpart = __shfl_xor(qval, 1);
            unsigned int kvp = (unsigned int)f2bf(kval)
                             | ((unsigned int)f2bf(vval) << 16);
            unsigned int qp  = (unsigned int)f2bf(qval)
                             | ((unsigned int)f2bf(qpart) << 16);
            if (n < N) {
                kv[(size_t)n * D + w * 16 + m] = kvp;            // 4x64B segs
                if (!(m & 1))
                    qtu[(size_t)n * 64 + w * 8 + (m >> 1)] = qp; // 4x32B segs
            }
        }
    }

    // --- row norms: waves 0..3 own rows w*16..w*16+15 (hA still live) ------
    if (w < 4) {
        for (int rr = 0; rr < 16; rr += 4) {
            float s0, s1, s2, s3;
            {
                unsigned int u0 = *(const unsigned int*)&hA[(w * 16 + rr + 0) * ASTR + lane * 2];
                unsigned int u1 = *(const unsigned int*)&hA[(w * 16 + rr + 1) * ASTR + lane * 2];
                unsigned int u2 = *(const unsigned int*)&hA[(w * 16 + rr + 2) * ASTR + lane * 2];
                unsigned int u3 = *(const unsigned int*)&hA[(w * 16 + rr + 3) * ASTR + lane * 2];
                float a, b;
                a = bf2f(u0); b = bf2f_hi(u0); s0 = a * a + b * b;
                a = bf2f(u1); b = bf2f_hi(u1); s1 = a * a + b * b;
                a = bf2f(u2); b = bf2f_hi(u2); s2 = a * a + b * b;
                a = bf2f(u3); b = bf2f_hi(u3); s3 = a * a + b * b;
            }
#pragma unroll
            for (int off = 1; off < 64; off <<= 1) {
                s0 += __shfl_xor(s0, off);
                s1 += __shfl_xor(s1, off);
                s2 += __shfl_xor(s2, off);
                s3 += __shfl_xor(s3, off);
            }
            if (lane < 4) {
                float sv = (lane == 0) ? s0 : (lane == 1) ? s1 : (lane == 2) ? s2 : s3;
                int n = row0 + w * 16 + rr + lane;
                if (n < N) inv_norm[n] = 1.0f / fmaxf(sqrtf(sv), 1e-12f);
            }
        }
    }
}

// ---------------------------------------------------------------------------
__global__ __launch_bounds__(1024) void scan_blocks_kernel(
    const unsigned char* __restrict__ sflag, const int* __restrict__ cnt_dst,
    int* __restrict__ rowptr, int* __restrict__ deg,
    int* __restrict__ btot, int* __restrict__ zcount, int N)
{
    __shared__ int wtot[16];
    __shared__ int wscan[16];
    int tid = threadIdx.x, lane = tid & 63, wv = tid >> 6;
    int i = blockIdx.x * 1024 + tid;
    int cs = 0, cd = 0;
    if (i < N) { cs = sflag[i]; cd = cnt_dst[i]; }
    int x = cd;
#pragma unroll
    for (int off = 1; off < 64; off <<= 1) {
        int y = __shfl_up(x, off);
        if (lane >= off) x += y;
    }
    if (lane == 63) wtot[wv] = x;
    __syncthreads();
    if (wv == 0) {
        int t = (lane < 16) ? wtot[lane] : 0;
#pragma unroll
        for (int off = 1; off < 16; off <<= 1) {
            int y = __shfl_up(t, off);
            if (lane >= off) t += y;
        }
        if (lane < 16) wscan[lane] = t;
    }
    __syncthreads();
    int woff = (wv == 0) ? 0 : wscan[wv - 1];
    if (i < N) {
        rowptr[i] = woff + x - cd;       // block-local prefix; +boff at use
        deg[i] = (cs | (cd > 0)) ? 1 : 0;
    }
    if (tid == 0) btot[blockIdx.x] = wscan[15];
    int zc = (i < N && cs == 0 && cd == 0) ? 1 : 0;
#pragma unroll
    for (int off = 1; off < 64; off <<= 1) zc += __shfl_xor(zc, off);
    if (lane == 0 && zc) atomicAdd(zcount, zc);
}

// ---------------------------------------------------------------------------
__global__ void scan_final_kernel(const int* __restrict__ btot,
                                  int* __restrict__ boff,
                                  const int* __restrict__ zcount,
                                  const float* __restrict__ fsb,
                                  float* __restrict__ flags, int N, int nb)
{
    int lane = threadIdx.x;   // 64
    int v = (lane < nb) ? btot[lane] : 0;
    int x = v;
#pragma unroll
    for (int off = 1; off < 64; off <<= 1) {
        int y = __shfl_up(x, off);
        if (lane >= off) x += y;
    }
    if (lane < nb) boff[lane] = x - v;
    if (lane == 0) {
        float z = (float)zcount[0];
        float sparsity = z / (float)N;
        flags[0] = (sparsity > 0.3f) ? fsb[0] : 0.f;
        flags[1] = fmaxf((float)N - z, 1.f);
    }
}

// ---------------------------------------------------------------------------
// r5: boff folded in (scan_add kernel deleted).
// ---------------------------------------------------------------------------
__global__ void scatter_kernel(const int* __restrict__ src, const int* __restrict__ dst,
                               const int* __restrict__ rowptr,
                               const int* __restrict__ boff, int* __restrict__ cursor,
                               int* __restrict__ esrc, int E)
{
    int e = blockIdx.x * blockDim.x + threadIdx.x;
    if (e >= E) return;
    int d = dst[e];
    int pos = rowptr[d] + boff[d >> 10] + atomicAdd(&cursor[d], 1);
    esrc[pos] = src[e];
}

// ---------------------------------------------------------------------------
// Fused softmax + aggregation, gather-based, ZERO atomics (r3 variant — best
// measured; r4's register-index shfl chain regressed).  One wave per dst
// node, 32 lanes/edge, 8 edges/iter (4 gathers in flight/half), tails 4/2/1.
// At the L3/fabric random-gather knee (~3.2 TB/s on 178 MB) -> ~57 us floor.
// ---------------------------------------------------------------------------
__global__ __launch_bounds__(256) void dst_agg_kernel(
    const unsigned int* __restrict__ kv, const unsigned short* __restrict__ qt,
    const float* __restrict__ h, const float* __restrict__ inv_norm,
    const int* __restrict__ rowptr, const int* __restrict__ boff,
    const int* __restrict__ esrc, const float* __restrict__ flags,
    unsigned int* __restrict__ agg, int N, int E)
{
    int n = (blockIdx.x * blockDim.x + threadIdx.x) >> 6;
    int lane = threadIdx.x & 63;
    if (n >= N) return;
    int half = lane >> 5, c = lane & 31;
    int beg = rowptr[n] + boff[n >> 10];
    int end = (n + 1 == N) ? E : rowptr[n + 1] + boff[(n + 1) >> 10];
    uint2 qw = *(const uint2*)(qt + (size_t)n * D + c * 4);
    float q0 = bf2f(qw.x), q1 = bf2f_hi(qw.x);
    float q2 = bf2f(qw.y), q3 = bf2f_hi(qw.y);
    float boost = flags[0];
    float hn0 = 0.f, hn1 = 0.f, hn2 = 0.f, hn3 = 0.f, innd = 0.f;
    if (boost != 0.f) {
        float4 hh = *(const float4*)(h + (size_t)n * D + c * 4);
        hn0 = hh.x; hn1 = hh.y; hn2 = hh.z; hn3 = hh.w; innd = inv_norm[n];
    }
    const float SC = 0.17677669529663687f;   // 1/sqrt(32)
    float a0 = 0.f, a1 = 0.f, a2 = 0.f, a3 = 0.f, den = 0.f;
    int i = beg;
    // ---- main: 8 edges / iteration (4 gathers in flight per half) ---------
    for (; i + 7 < end; i += 8) {
        int sA = esrc[i + half];
        int sB = esrc[i + 2 + half];
        int sC = esrc[i + 4 + half];
        int sD = esrc[i + 6 + half];
        uint4 wA = *(const uint4*)(kv + (size_t)sA * D + c * 4);
        uint4 wB = *(const uint4*)(kv + (size_t)sB * D + c * 4);
        uint4 wC = *(const uint4*)(kv + (size_t)sC * D + c * 4);
        uint4 wD = *(const uint4*)(kv + (size_t)sD * D + c * 4);
        float dA = q0 * bf2f(wA.x) + q1 * bf2f(wA.y)
                 + q2 * bf2f(wA.z) + q3 * bf2f(wA.w);
        float dB = q0 * bf2f(wB.x) + q1 * bf2f(wB.y)
                 + q2 * bf2f(wB.z) + q3 * bf2f(wB.w);
        float dC = q0 * bf2f(wC.x) + q1 * bf2f(wC.y)
                 + q2 * bf2f(wC.z) + q3 * bf2f(wC.w);
        float dD = q0 * bf2f(wD.x) + q1 * bf2f(wD.y)
                 + q2 * bf2f(wD.z) + q3 * bf2f(wD.w);
        dA += __shfl_xor(dA, 1);  dB += __shfl_xor(dB, 1);
        dC += __shfl_xor(dC, 1);  dD += __shfl_xor(dD, 1);
        dA += __shfl_xor(dA, 2);  dB += __shfl_xor(dB, 2);
        dC += __shfl_xor(dC, 2);  dD += __shfl_xor(dD, 2);
        dA += __shfl_xor(dA, 4);  dB += __shfl_xor(dB, 4);
        dC += __shfl_xor(dC, 4);  dD += __shfl_xor(dD, 4);
        float attA = dA * SC, attB = dB * SC;
        float attC = dC * SC, attD = dD * SC;
        if (boost != 0.f) {
            float4 xA = *(const float4*)(h + (size_t)sA * D + c * 4);
            float4 xB = *(const float4*)(h + (size_t)sB * D + c * 4);
            float4 xC = *(const float4*)(h + (size_t)sC * D + c * 4);
            float4 xD = *(const float4*)(h + (size_t)sD * D + c * 4);
            float fA = hn0 * xA.x + hn1 * xA.y + hn2 * xA.z + hn3 * xA.w;
            float fB = hn0 * xB.x + hn1 * xB.y + hn2 * xB.z + hn3 * xB.w;
            float fC = hn0 * xC.x + hn1 * xC.y + hn2 * xC.z + hn3 * xC.w;
            float fD = hn0 * xD.x + hn1 * xD.y + hn2 * xD.z + hn3 * xD.w;
#pragma unroll
            for (int off = 1; off < 32; off <<= 1) {
                fA += __shfl_xor(fA, off);
                fB += __shfl_xor(fB, off);
                fC += __shfl_xor(fC, off);
                fD += __shfl_xor(fD, off);
            }
            attA += fA * inv_norm[sA] * innd * boost;
            attB += fB * inv_norm[sB] * innd * boost;
            attC += fC * inv_norm[sC] * innd * boost;
            attD += fD * inv_norm[sD] * innd * boost;
        }
        attA = fminf(fmaxf(attA, -60.f), 60.f);
        attB = fminf(fmaxf(attB, -60.f), 60.f);
        attC = fminf(fmaxf(attC, -60.f), 60.f);
        attD = fminf(fmaxf(attD, -60.f), 60.f);
        float pA = __expf(attA), pB = __expf(attB);
        float pC = __expf(attC), pD = __expf(attD);
        den += (pA + pB) + (pC + pD);
        a0 += pA * bf2f_hi(wA.x) + pB * bf2f_hi(wB.x)
            + pC * bf2f_hi(wC.x) + pD * bf2f_hi(wD.x);
        a1 += pA * bf2f_hi(wA.y) + pB * bf2f_hi(wB.y)
            + pC * bf2f_hi(wC.y) + pD * bf2f_hi(wD.y);
        a2 += pA * bf2f_hi(wA.z) + pB * bf2f_hi(wB.z)
            + pC * bf2f_hi(wC.z) + pD * bf2f_hi(wD.z);
        a3 += pA * bf2f_hi(wA.w) + pB * bf2f_hi(wB.w)
            + pC * bf2f_hi(wC.w) + pD * bf2f_hi(wD.w);
    }
    // ---- tail: 4 edges ----------------------------------------------------
    for (; i + 3 < end; i += 4) {
        int sA = esrc[i + half];
        int sB = esrc[i + 2 + half];
        uint4 wA = *(const uint4*)(kv + (size_t)sA * D + c * 4);
        uint4 wB = *(const uint4*)(kv + (size_t)sB * D + c * 4);
        float dA = q0 * bf2f(wA.x) + q1 * bf2f(wA.y)
                 + q2 * bf2f(wA.z) + q3 * bf2f(wA.w);
        float dB = q0 * bf2f(wB.x) + q1 * bf2f(wB.y)
                 + q2 * bf2f(wB.z) + q3 * bf2f(wB.w);
        dA += __shfl_xor(dA, 1);  dB += __shfl_xor(dB, 1);
        dA += __shfl_xor(dA, 2);  dB += __shfl_xor(dB, 2);
        dA += __shfl_xor(dA, 4);  dB += __shfl_xor(dB, 4);
        float attA = dA * SC, attB = dB * SC;
        if (boost != 0.f) {
            float4 xA = *(const float4*)(h + (size_t)sA * D + c * 4);
            float4 xB = *(const float4*)(h + (size_t)sB * D + c * 4);
            float fA = hn0 * xA.x + hn1 * xA.y + hn2 * xA.z + hn3 * xA.w;
            float fB = hn0 * xB.x + hn1 * xB.y + hn2 * xB.z + hn3 * xB.w;
#pragma unroll
            for (int off = 1; off < 32; off <<= 1) {
                fA += __shfl_xor(fA, off);
                fB += __shfl_xor(fB, off);
            }
            attA += fA * inv_norm[sA] * innd * boost;
            attB += fB * inv_norm[sB] * innd * boost;
        }
        attA = fminf(fmaxf(attA, -60.f), 60.f);
        attB = fminf(fmaxf(attB, -60.f), 60.f);
        float pA = __expf(attA), pB = __expf(attB);
        den += pA + pB;
        a0 += pA * bf2f_hi(wA.x) + pB * bf2f_hi(wB.x);
        a1 += pA * bf2f_hi(wA.y) + pB * bf2f_hi(wB.y);
        a2 += pA * bf2f_hi(wA.z) + pB * bf2f_hi(wB.z);
        a3 += pA * bf2f_hi(wA.w) + pB * bf2f_hi(wB.w);
    }
    for (; i + 1 < end; i += 2) {
        int sA = esrc[i + half];
        uint4 wA = *(const uint4*)(kv + (size_t)sA * D + c * 4);
        float dA = q0 * bf2f(wA.x) + q1 * bf2f(wA.y)
                 + q2 * bf2f(wA.z) + q3 * bf2f(wA.w);
        dA += __shfl_xor(dA, 1);
        dA += __shfl_xor(dA, 2);
        dA += __shfl_xor(dA, 4);
        float attA = dA * SC;
        if (boost != 0.f) {
            float4 xA = *(const float4*)(h + (size_t)sA * D + c * 4);
            float fA = hn0 * xA.x + hn1 * xA.y + hn2 * xA.z + hn3 * xA.w;
#pragma unroll
            for (int off = 1; off < 32; off <<= 1) fA += __shfl_xor(fA, off);
            attA += fA * inv_norm[sA] * innd * boost;
        }
        attA = fminf(fmaxf(attA, -60.f), 60.f);
        float pA = __expf(attA);
        den += pA;
        a0 += pA * bf2f_hi(wA.x);
        a1 += pA * bf2f_hi(wA.y);
        a2 += pA * bf2f_hi(wA.z);
        a3 += pA * bf2f_hi(wA.w);
    }
    if (i < end && half == 0) {
        int sA = esrc[i];
        uint4 wA = *(const uint4*)(kv + (size_t)sA * D + c * 4);
        float dA = q0 * bf2f(wA.x) + q1 * bf2f(wA.y)
                 + q2 * bf2f(wA.z) + q3 * bf2f(wA.w);
        dA += __shfl_xor(dA, 1);
        dA += __shfl_xor(dA, 2);
        dA += __shfl_xor(dA, 4);
        float attA = dA * SC;
        if (boost != 0.f) {
            float4 xA = *(const float4*)(h + (size_t)sA * D + c * 4);
            float fA = hn0 * xA.x + hn1 * xA.y + hn2 * xA.z + hn3 * xA.w;
#pragma unroll
            for (int off = 1; off < 32; off <<= 1) fA += __shfl_xor(fA, off);
            attA += fA * inv_norm[sA] * innd * boost;
        }
        attA = fminf(fmaxf(attA, -60.f), 60.f);
        float pA = __expf(attA);
        den += pA;
        a0 += pA * bf2f_hi(wA.x);
        a1 += pA * bf2f_hi(wA.y);
        a2 += pA * bf2f_hi(wA.z);
        a3 += pA * bf2f_hi(wA.w);
    }
    den += __shfl_xor(den, 32);
    a0  += __shfl_xor(a0, 32);
    a1  += __shfl_xor(a1, 32);
    a2  += __shfl_xor(a2, 32);
    a3  += __shfl_xor(a3, 32);
    if (half == 0) {
        float r = 1.0f / fmaxf(den, 1e-38f);
        uint2 o;
        o.x = (unsigned int)f2bf(a0 * r) | ((unsigned int)f2bf(a1 * r) << 16);
        o.y = (unsigned int)f2bf(a2 * r) | ((unsigned int)f2bf(a3 * r) << 16);
        *(uint2*)(agg + (size_t)n * (D / 2) + c * 2) = o;
    }
}

// ---------------------------------------------------------------------------
// out = LN(agg @ Wa + ba) via MFMA.  r4 structure (wave-per-column-slice,
// weights loaded once, pinned; separate os buffer; LN rows 8/wave).
// ---------------------------------------------------------------------------
__global__ __launch_bounds__(512) void out_ln_kernel(
    const unsigned int* __restrict__ agg,      // packed bf16 pairs
    const unsigned short* __restrict__ WaT, const float* __restrict__ ba,
    const float* __restrict__ ln_g, const float* __restrict__ ln_b,
    const int* __restrict__ deg, float* __restrict__ out,
    float* __restrict__ gcpart, int N)
{
    __shared__ unsigned short aB[64 * ASTR];   // 17.4 KB staged agg
    __shared__ unsigned short os[64 * ASTR];   // 17.4 KB pre-LN values
    int row0 = blockIdx.x * 64;
    int tid = threadIdx.x;
    int lane = tid & 63, w = tid >> 6;
    int m = lane & 15, quad = lane >> 4;

    // --- this wave's 4 Wa fragments (col-slice = w), issued up front -------
    int j = w * 16 + m;
    const unsigned short* wb = WaT + (size_t)j * D + quad * 8;
    short8 B0 = *(const short8*)(wb);
    short8 B1 = *(const short8*)(wb + 32);
    short8 B2 = *(const short8*)(wb + 64);
    short8 B3 = *(const short8*)(wb + 96);
    float bj = ba[j];
    __builtin_amdgcn_sched_barrier(0);

    // --- stage agg into LDS ------------------------------------------------
    for (int i = tid; i < 64 * 16; i += 512) {
        int r = i >> 4, c8 = (i & 15) << 3;
        int n = row0 + r;
        uint4 v = make_uint4(0u, 0u, 0u, 0u);
        if (n < N) v = *(const uint4*)(agg + (size_t)n * (D / 2) + (c8 >> 1));
        *(uint4*)&aB[r * ASTR + c8] = v;
    }
    __syncthreads();

#pragma unroll
    for (int tile = 0; tile < 4; tile++) {
        const unsigned short* ab = &aB[(tile * 16 + m) * ASTR + quad * 8];
        short8 a0 = *(const short8*)(ab);
        short8 a1 = *(const short8*)(ab + 32);
        short8 a2 = *(const short8*)(ab + 64);
        short8 a3 = *(const short8*)(ab + 96);
        floatx4 acc = (floatx4){0.f, 0.f, 0.f, 0.f};
        acc = __builtin_amdgcn_mfma_f32_16x16x32_bf16(a0, B0, acc, 0, 0, 0);
        acc = __builtin_amdgcn_mfma_f32_16x16x32_bf16(a1, B1, acc, 0, 0, 0);
        acc = __builtin_amdgcn_mfma_f32_16x16x32_bf16(a2, B2, acc, 0, 0, 0);
        acc = __builtin_amdgcn_mfma_f32_16x16x32_bf16(a3, B3, acc, 0, 0, 0);
#pragma unroll
        for (int r = 0; r < 4; r++)
            os[(tile * 16 + quad * 4 + r) * ASTR + j] = f2bf(acc[r] + bj);
    }
    __syncthreads();

    // --- LN phase: wave w owns rows w*8 .. w*8+7 ---------------------------
    int j2 = lane * 2;
    float g0 = ln_g[j2], g1 = ln_g[j2 + 1];
    float b0 = ln_b[j2], b1 = ln_b[j2 + 1];
    float gcs0 = 0.f, gcs1 = 0.f;
    for (int rr = 0; rr < 8; rr++) {
        int r = w * 8 + rr;
        int n = row0 + r;
        if (n >= N) break;
        unsigned int u = *(const unsigned int*)&os[r * ASTR + j2];
        float x0 = bf2f(u), x1 = bf2f_hi(u);
        float s = x0 + x1, s2 = x0 * x0 + x1 * x1;
#pragma unroll
        for (int off = 1; off < 64; off <<= 1) {
            s  += __shfl_xor(s, off);
            s2 += __shfl_xor(s2, off);
        }
        float mu = s * (1.f / 128.f);
        float var = s2 * (1.f / 128.f) - mu * mu;
        float rstd = rsqrtf(fmaxf(var, 0.f) + 1e-5f);
        float y0 = (x0 - mu) * rstd * g0 + b0;
        float y1 = (x1 - mu) * rstd * g1 + b1;
        *(float2*)(out + (size_t)n * D + j2) = make_float2(y0, y1);
        if (deg[n] != 0) { gcs0 += y0; gcs1 += y1; }
    }
    int slot = blockIdx.x & 63;
    if (gcs0 != 0.f || gcs1 != 0.f) {
        atomicAdd(&gcpart[slot * D + j2],     gcs0);
        atomicAdd(&gcpart[slot * D + j2 + 1], gcs1);
    }
}

// ---------------------------------------------------------------------------
// r5: gc_final folded in — each block redundantly reduces the 32 KB gcpart
// (L2-hot, ~0.2 us aggregate) into LDS, then fixes up zero-degree rows.
// ---------------------------------------------------------------------------
__global__ __launch_bounds__(256) void fixup_kernel(
    const float* __restrict__ h, const int* __restrict__ deg,
    const float* __restrict__ gcpart, const float* __restrict__ flags,
    float* __restrict__ out, int N)
{
    __shared__ float gcs[D];
    int tid = threadIdx.x;
    if (tid < D) {
        float s = 0.f;
        for (int i = 0; i < 64; i++) s += gcpart[i * D + tid];
        gcs[tid] = s / flags[1];
    }
    __syncthreads();
    int n = blockIdx.x * 256 + tid;
    if (n >= N) return;
    if (deg[n] != 0) return;
    for (int j = 0; j < D; j += 4) {
        float4 hv = *(const float4*)(h + (size_t)n * D + j);
        float4 o;
        o.x = 0.9f * hv.x + 0.1f * gcs[j];
        o.y = 0.9f * hv.y + 0.1f * gcs[j + 1];
        o.z = 0.9f * hv.z + 0.1f * gcs[j + 2];
        o.w = 0.9f * hv.w + 0.1f * gcs[j + 3];
        *(float4*)(out + (size_t)n * D + j) = o;
    }
}

// ---------------------------------------------------------------------------
extern "C" void kernel_launch(void* const* d_in, const int* in_sizes, int n_in,
                              void* d_out, int out_size, void* d_ws, size_t ws_size,
                              hipStream_t stream)
{
    const float* h       = (const float*)d_in[0];
    const int* src_idx   = (const int*)d_in[1];
    const int* dst_idx   = (const int*)d_in[2];
    const float* Wk      = (const float*)d_in[3];
    const float* bk      = (const float*)d_in[4];
    const float* Wq      = (const float*)d_in[5];
    const float* bq      = (const float*)d_in[6];
    const float* Wv      = (const float*)d_in[7];
    const float* bv      = (const float*)d_in[8];
    const float* rk      = (const float*)d_in[9];
    const float* rq      = (const float*)d_in[10];
    const float* rv      = (const float*)d_in[11];
    const float* Wa      = (const float*)d_in[12];
    const float* ba      = (const float*)d_in[13];
    const float* ln_g    = (const float*)d_in[14];
    const float* ln_b    = (const float*)d_in[15];
    const float* fsb     = (const float*)d_in[16];
    float* out           = (float*)d_out;

    int N = in_sizes[0] / D;
    int E = in_sizes[1];
    int nb = (N + 1023) >> 10;   // scan blocks (<= 64)
    int nG = (N + 63) / 64;      // gemm blocks
    int nH = (E + 511) / 512;    // hist blocks

    // ---- workspace: small control buffers first ---------------------------
    char* p = (char*)d_ws;
    auto alloc = [&](size_t bytes) { char* q = p; p += (bytes + 15) & ~(size_t)15; return q; };

    unsigned short* WpT = (unsigned short*)alloc(3 * D * D * 2);
    unsigned short* WaT = (unsigned short*)alloc(D * D * 2);
    float* bp       = (float*)alloc(3 * D * 4);
    float* flags    = (float*)alloc(2 * 4);
    int*   btot     = (int*)alloc(64 * 4);
    int*   boff     = (int*)alloc(64 * 4);
    float* inv_norm = (float*)alloc((size_t)N * 4);
    int*   rowptr   = (int*)alloc(((size_t)N + 1) * 4);
    int*   deg      = (int*)alloc((size_t)N * 4);
    // zero region: sflag, cnt_dst, cursor, zcount, gcpart (contiguous)
    char* z1 = p;
    unsigned char* sflag = (unsigned char*)alloc((size_t)N);
    int*   cnt_dst = (int*)alloc((size_t)N * 4);
    int*   cursor  = (int*)alloc((size_t)N * 4);
    int*   zcount  = (int*)alloc(4);
    float* gcpart  = (float*)alloc(64 * D * 4);
    size_t z1_bytes = (size_t)(p - z1);
    // big arrays
    unsigned short* qt = (unsigned short*)alloc((size_t)N * D * 2);
    unsigned int*   kv = (unsigned int*)alloc((size_t)N * D * 4);
    int*   esrc        = (int*)alloc((size_t)E * 4);
    unsigned int* agg  = (unsigned int*)alloc((size_t)N * D * 2);

    hipMemsetAsync(z1, 0, z1_bytes, stream);

    prep_weights_kernel<<<dim3(129, 4), 128, 0, stream>>>(Wk, bk, Wq, bq, Wv, bv,
                                                          rk, rq, rv, Wa,
                                                          WpT, WaT, bp);
    gemm_hist_kernel<<<nG + nH, 512, 0, stream>>>(h, WpT, bp, qt, kv, inv_norm,
                                                  src_idx, dst_idx, sflag,
                                                  cnt_dst, N, E, nG);
    scan_blocks_kernel<<<nb, 1024, 0, stream>>>(sflag, cnt_dst, rowptr, deg,
                                                btot, zcount, N);
    scan_final_kernel<<<1, 64, 0, stream>>>(btot, boff, zcount, fsb,
                                            flags, N, nb);
    scatter_kernel<<<(E + 255) / 256, 256, 0, stream>>>(src_idx, dst_idx, rowptr,
                                                        boff, cursor, esrc, E);
    dst_agg_kernel<<<(N + 3) / 4, 256, 0, stream>>>(kv, qt, h, inv_norm,
                                                    rowptr, boff, esrc, flags,
                                                    agg, N, E);
    out_ln_kernel<<<(N + 63) / 64, 512, 0, stream>>>(agg, WaT, ba, ln_g, ln_b,
                                                     deg, out, gcpart, N);
    fixup_kernel<<<(N + 255) / 256, 256, 0, stream>>>(h, deg, gcpart, flags,
                                                      out, N);
}